// Round 9
// baseline (620.834 us; speedup 1.0000x reference)
//
#include <hip/hip_runtime.h>

#define KCODES 4096
#define DIM    256
#define NROWS  65536
#define MARGIN 4.0e-4f
#define DSLACK 3.0e-5f
#define LCAP   4096
#define LSTRIDE (DIM + 4)

typedef unsigned long long u64;
typedef unsigned int  uint;
typedef unsigned short ushort;
typedef __attribute__((ext_vector_type(8))) short bf16x8;
typedef __attribute__((ext_vector_type(4))) float f32x4;

typedef __attribute__((address_space(3))) uint lds_u32_t;
typedef __attribute__((address_space(1))) uint glb_u32_t;

__device__ __forceinline__ void g2lds16(const void* g, void* l) {
    __builtin_amdgcn_global_load_lds((const glb_u32_t*)g, (lds_u32_t*)l, 16, 0, 0);
}

// cross-lane mins via DPP (VALU pipe, no LDS)
__device__ __forceinline__ float dppmin_quad(float m) {
    m = fminf(m, __int_as_float(__builtin_amdgcn_update_dpp(0, __float_as_int(m), 0xB1, 0xF, 0xF, true)));
    m = fminf(m, __int_as_float(__builtin_amdgcn_update_dpp(0, __float_as_int(m), 0x4E, 0xF, 0xF, true)));
    return m;
}
__device__ __forceinline__ float dppmin_row16(float m) {
    m = fminf(m, __int_as_float(__builtin_amdgcn_update_dpp(0, __float_as_int(m), 0x124, 0xF, 0xF, true)));
    m = fminf(m, __int_as_float(__builtin_amdgcn_update_dpp(0, __float_as_int(m), 0x128, 0xF, 0xF, true)));
    return m;
}
__device__ __forceinline__ uint dppor_row16(uint v) {
    v |= (uint)__builtin_amdgcn_update_dpp(0, (int)v, 0x124, 0xF, 0xF, true);
    v |= (uint)__builtin_amdgcn_update_dpp(0, (int)v, 0x128, 0xF, 0xF, true);
    return v;
}

// ============================ shared helpers ============================

__device__ __forceinline__ float np_half_sum128(const float4* __restrict__ p4) {
    #pragma clang fp contract(off)
    float4 v0 = p4[0], v1 = p4[1];
    float r0 = v0.x * v0.x, r1 = v0.y * v0.y, r2 = v0.z * v0.z, r3 = v0.w * v0.w;
    float r4 = v1.x * v1.x, r5 = v1.y * v1.y, r6 = v1.z * v1.z, r7 = v1.w * v1.w;
    #pragma unroll
    for (int i = 1; i < 16; ++i) {
        float4 a = p4[2 * i], b = p4[2 * i + 1];
        r0 += a.x * a.x; r1 += a.y * a.y; r2 += a.z * a.z; r3 += a.w * a.w;
        r4 += b.x * b.x; r5 += b.y * b.y; r6 += b.z * b.z; r7 += b.w * b.w;
    }
    return ((r0 + r1) + (r2 + r3)) + ((r4 + r5) + (r6 + r7));
}

__global__ void k_rownorm(const float* __restrict__ src, float* __restrict__ dst, int nrows) {
    int r = blockIdx.x * blockDim.x + threadIdx.x;
    if (r >= nrows) return;
    const float4* p4 = (const float4*)(src + (size_t)r * DIM);
    float s;
    {
        #pragma clang fp contract(off)
        s = np_half_sum128(p4) + np_half_sum128(p4 + 32);
    }
    dst[r] = s;
}

// validated (round 3): fl32( fl32(Cr+ebc) - fl32(2*fl32(cross_exact)) )
__device__ __forceinline__ float f32_dist(float Cr, float ebc, double accv) {
    #pragma clang fp contract(off)
    float A = Cr + ebc;
    float B = 2.0f * (float)accv;
    return A - B;
}

__device__ __forceinline__ ushort f2bf(float f) {
    uint u = __float_as_uint(f);
    return (ushort)((u + 0x7fffu + ((u >> 16) & 1u)) >> 16);
}

// ============================ fast-path kernels ============================

__global__ void k_split(const float* __restrict__ src, ushort* __restrict__ dst, int n8) {
    int i = blockIdx.x * blockDim.x + threadIdx.x;
    if (i >= n8) return;
    const float4* s4 = (const float4*)src;
    float4 a = s4[2 * i], b = s4[2 * i + 1];
    uint4 ov;
    ov.x = (uint)f2bf(a.x) | ((uint)f2bf(a.y) << 16);
    ov.y = (uint)f2bf(a.z) | ((uint)f2bf(a.w) << 16);
    ov.z = (uint)f2bf(b.x) | ((uint)f2bf(b.y) << 16);
    ov.w = (uint)f2bf(b.z) | ((uint)f2bf(b.w) << 16);
    *(uint4*)&dst[8 * i] = ov;
}

__global__ void k_init(int* __restrict__ cnt) {
    cnt[threadIdx.x] = 0;
}

// MFMA filter: z in registers (64 rows/wave, full K); e streamed as 64-code
// double-buffered swizzled LDS tiles (2x32KB => 2 blocks/CU, 2 waves/SIMD).
// Grid 512: rb = bid&255 (256 rows), cb = bid>>8 (2048-code half).
// tk output granularity unchanged: 128-code tiles (= pair of LDS tiles,
// merged via mprev registers), quad-subtile u8 deltas as before.
__global__ __launch_bounds__(256, 2)
void k_gemm(const ushort* __restrict__ zh, const ushort* __restrict__ eh,
            const float* __restrict__ Crow, const float* __restrict__ eb2,
            float* __restrict__ tk, uint* __restrict__ tk2) {
    __shared__ __align__(16) ushort Bs[2][64 * 256];   // 2 x 32KB

    const int t = threadIdx.x;
    const int lane = t & 63;
    const int w = t >> 6;
    const int l15 = lane & 15, l4 = lane >> 4;
    const int rb = blockIdx.x & 255;
    const int cb = blockIdx.x >> 8;               // 0/1: code half
    const int row0w = rb * 256 + w * 64;
    const int code0 = cb * 2048;

    const char* ebp = (const char*)eh + (size_t)code0 * 512;

    // stage 64-code tile ct2 (0..31): linear LDS dest, inverse-swizzled source
    auto stage = [&](int buf, int ct2) {
        const char* base = ebp + (size_t)ct2 * 64 * 512;
        #pragma unroll
        for (int i = 0; i < 8; ++i) {
            int idx = i * 256 + t;            // 0..2047 16B-chunks
            int code = idx >> 5;
            int c16  = idx & 31;
            int src  = (code << 9) + ((c16 ^ (code & 7)) << 4);
            g2lds16(base + src, (char*)Bs[buf] + idx * 16);
        }
    };

    // ---- A: 64 rows x 256 K in registers (MFMA A-frag layout) ----
    bf16x8 a[4][8];
    #pragma unroll
    for (int f = 0; f < 4; ++f)
        #pragma unroll
        for (int ks = 0; ks < 8; ++ks)
            a[f][ks] = *(const bf16x8*)&zh[(size_t)(row0w + f * 16 + l15) * 256 + ks * 32 + l4 * 8];

    float crf[16];
    #pragma unroll
    for (int f = 0; f < 4; ++f)
        #pragma unroll
        for (int rg = 0; rg < 4; ++rg)
            crf[f * 4 + rg] = Crow[row0w + f * 16 + l4 * 4 + rg];

    float mprev[16];

    stage(0, 0);
    __syncthreads();

    #pragma unroll 2
    for (int ct2 = 0; ct2 < 32; ++ct2) {
        int buf = ct2 & 1;
        if (ct2 < 31) stage(buf ^ 1, ct2 + 1);

        f32x4 acc[4][4];
        #pragma unroll
        for (int f = 0; f < 4; ++f)
            #pragma unroll
            for (int cg = 0; cg < 4; ++cg) acc[f][cg] = (f32x4){0.f, 0.f, 0.f, 0.f};

        const ushort* Bb = Bs[buf];
        #pragma unroll
        for (int ks = 0; ks < 8; ++ks) {
            bf16x8 bfv[4];
            #pragma unroll
            for (int cg = 0; cg < 4; ++cg) {
                int rB = cg * 16 + l15;
                int off = rB * 256 + ((ks * 32 + l4 * 8) ^ ((l15 & 7) << 3));
                bfv[cg] = *(const bf16x8*)&Bb[off];
            }
            #pragma unroll
            for (int f = 0; f < 4; ++f)
                #pragma unroll
                for (int cg = 0; cg < 4; ++cg)
                    acc[f][cg] = __builtin_amdgcn_mfma_f32_16x16x32_bf16(
                        a[f][ks], bfv[cg], acc[f][cg], 0, 0, 0);
        }

        // ---- epilogue: quad-subtile mins; merge tile pairs into 128-code tk ----
        float ebv[4];
        #pragma unroll
        for (int cg = 0; cg < 4; ++cg) ebv[cg] = eb2[code0 + ct2 * 64 + cg * 16 + l15];

        #pragma unroll
        for (int f = 0; f < 4; ++f) {
            #pragma unroll
            for (int rg = 0; rg < 4; ++rg) {
                float m;
                {
                    #pragma clang fp contract(off)
                    m = 1e38f;
                    #pragma unroll
                    for (int cg = 0; cg < 4; ++cg) {
                        float A = crf[f * 4 + rg] + ebv[cg];
                        float d = A - 2.0f * acc[f][cg][rg];
                        m = fminf(m, d);
                    }
                }
                m = dppmin_quad(m);              // quad-subtile min (this half)
                if ((ct2 & 1) == 0) {
                    mprev[f * 4 + rg] = m;
                } else {
                    m = fminf(m, mprev[f * 4 + rg]);   // merge 128-code tile
                    float mt = dppmin_row16(m);
                    int q = (int)((m - mt) * 1e5f);
                    q = q > 255 ? 255 : q;
                    uint pk = (uint)q << (8 * (l15 >> 2));
                    pk = dppor_row16(pk);
                    if (l15 == 0) {
                        int grow = row0w + f * 16 + l4 * 4 + rg;
                        int tt = cb * 16 + (ct2 >> 1);
                        tk [(size_t)tt * NROWS + grow] = mt;
                        tk2[(size_t)tt * NROWS + grow] = pk;
                    }
                }
            }
        }
        __syncthreads();
    }
}

// per row: rowbest over 32 tile-mins; decode subtile mins; staggered sweep +
// wave-aggregated list append; init fkey.
__global__ void k_lists(const float* __restrict__ tk, const uint* __restrict__ tk2,
                        int* __restrict__ cnt, int* __restrict__ list,
                        u64* __restrict__ fkey) {
    int row = blockIdx.x * 256 + threadIdx.x;
    int lane = threadIdx.x & 63;
    float best = __int_as_float(0x7f800000);
    for (int tt = 0; tt < 32; ++tt)
        best = fminf(best, tk[(size_t)tt * NROWS + row]);
    fkey[row] = ~0ull;
    float cutoff = best + (MARGIN + DSLACK);

    int wid = (blockIdx.x << 2) | (threadIdx.x >> 6);
    int off = (wid * 13) & 31;
    for (int g = 0; g < 32; ++g) {
        int tt = (g + off) & 31;
        float tm = tk [(size_t)tt * NROWS + row];
        uint  pk = tk2[(size_t)tt * NROWS + row];
        #pragma unroll
        for (int p = 0; p < 4; ++p) {
            float v = tm + (float)((pk >> (8 * p)) & 255u) * 1e-5f;
            bool pred = v <= cutoff;
            u64 mask = __ballot(pred);
            if (mask) {
                int sub = tt * 4 + p;
                int nq = __popcll(mask);
                int rank = __popcll(mask & ((1ull << lane) - 1ull));
                int base = 0;
                if (lane == 0) base = atomicAdd(&cnt[sub], nq);
                base = __shfl(base, 0, 64);
                int pos = base + rank;
                if (pred && pos < LCAP) list[sub * LCAP + pos] = row;
            }
        }
    }
}

// exact decider; subtile sub = (tile<<2)|quad: codes = tile*128+cg*16+quad*4+r.
// Validated f64-cross + f32_dist + lexicographic (d,idx) key, atomicMin-merged.
__global__ __launch_bounds__(256, 2)
void k_exact(const float* __restrict__ z, const float* __restrict__ e,
             const float* __restrict__ Crow, const float* __restrict__ eb2,
             const int* __restrict__ list, const int* __restrict__ cnt,
             u64* __restrict__ fkey) {
    __shared__ __align__(16) float ex[32][260];
    __shared__ __align__(16) float zx[32][260];
    __shared__ int rows[32];
    __shared__ u64 keytab[32][17];
    const int sub = blockIdx.x;       // 0..127
    const int tile = sub >> 2, qq = sub & 3;
    const int nct = cnt[sub];
    const int t = threadIdx.x;
    const int rp = t & 15, cs = t >> 4;

    {   // stage e subtile (32 quad-mapped codes x 256)
        int cc = t >> 3, c8 = t & 7;
        int gcode = tile * 128 + (cc >> 2) * 16 + qq * 4 + (cc & 3);
        const float4* src = (const float4*)(e + (size_t)gcode * DIM);
        float4* dr = (float4*)ex[cc];
        #pragma unroll
        for (int j = 0; j < 8; ++j) dr[c8 + 8 * j] = src[c8 + 8 * j];
    }
    const int gc0 = tile * 128 + (cs >> 2) * 16 + qq * 4 + (cs & 3);
    const int gc1 = tile * 128 + ((cs >> 2) + 4) * 16 + qq * 4 + (cs & 3);
    const float ebc0 = eb2[gc0];
    const float ebc1 = eb2[gc1];

    for (int base = blockIdx.y * 32; base < nct; base += gridDim.y * 32) {
        __syncthreads();
        if (t < 32) {
            int i = base + t;
            rows[t] = list[sub * LCAP + (i < nct ? i : nct - 1)];
        }
        __syncthreads();
        {
            int rr = t >> 3, c8 = t & 7;
            const float4* src = (const float4*)(z + (size_t)rows[rr] * DIM);
            float4* dr = (float4*)zx[rr];
            #pragma unroll
            for (int j = 0; j < 8; ++j) dr[c8 + 8 * j] = src[c8 + 8 * j];
        }
        __syncthreads();

        double a00 = 0.0, a01 = 0.0, a10 = 0.0, a11 = 0.0;
        const float4* z0 = (const float4*)zx[rp];
        const float4* z1 = (const float4*)zx[rp + 16];
        const float4* e0 = (const float4*)ex[cs];
        const float4* e1 = (const float4*)ex[cs + 16];
        #pragma unroll 8
        for (int d4 = 0; d4 < 64; ++d4) {
            float4 x0 = z0[d4], x1 = z1[d4], y0 = e0[d4], y1 = e1[d4];
            a00 += (double)x0.x * (double)y0.x; a00 += (double)x0.y * (double)y0.y;
            a00 += (double)x0.z * (double)y0.z; a00 += (double)x0.w * (double)y0.w;
            a01 += (double)x0.x * (double)y1.x; a01 += (double)x0.y * (double)y1.y;
            a01 += (double)x0.z * (double)y1.z; a01 += (double)x0.w * (double)y1.w;
            a10 += (double)x1.x * (double)y0.x; a10 += (double)x1.y * (double)y0.y;
            a10 += (double)x1.z * (double)y0.z; a10 += (double)x1.w * (double)y0.w;
            a11 += (double)x1.x * (double)y1.x; a11 += (double)x1.y * (double)y1.y;
            a11 += (double)x1.z * (double)y1.z; a11 += (double)x1.w * (double)y1.w;
        }
        int r0 = rows[rp], r1 = rows[rp + 16];
        float C0 = Crow[r0], C1 = Crow[r1];
        u64 k00 = ((u64)__float_as_uint(f32_dist(C0, ebc0, a00)) << 32) | (u64)gc0;
        u64 k01 = ((u64)__float_as_uint(f32_dist(C0, ebc1, a01)) << 32) | (u64)gc1;
        u64 k10 = ((u64)__float_as_uint(f32_dist(C1, ebc0, a10)) << 32) | (u64)gc0;
        u64 k11 = ((u64)__float_as_uint(f32_dist(C1, ebc1, a11)) << 32) | (u64)gc1;
        keytab[rp][cs]      = k00 < k01 ? k00 : k01;
        keytab[rp + 16][cs] = k10 < k11 ? k10 : k11;
        __syncthreads();
        if (t < 32) {
            u64 kb = keytab[t][0];
            #pragma unroll
            for (int j = 1; j < 16; ++j) {
                u64 k = keytab[t][j];
                kb = k < kb ? k : kb;
            }
            atomicMin((unsigned long long*)&fkey[rows[t]], kb);
        }
    }
}

__global__ __launch_bounds__(256)
void k_gather(const float* __restrict__ z, const float* __restrict__ e,
              const u64* __restrict__ fkey, float* __restrict__ out,
              double* __restrict__ partial) {
    __shared__ double lred[4];
    const int t = threadIdx.x;
    const int row = blockIdx.x * 32 + (t >> 3);
    const int c8 = t & 7;
    const int idx = (int)(fkey[row] & 0xffffffffull);
    if (c8 == 0) out[1 + (size_t)NROWS * DIM + row] = (float)idx;
    const float4* zr = (const float4*)(z + (size_t)row * DIM);
    const float4* er = (const float4*)(e + (size_t)idx * DIM);
    float4* orow = (float4*)(out + 1 + (size_t)row * DIM);
    double lacc = 0.0;
    #pragma unroll
    for (int j = 0; j < 8; ++j) {
        float4 q = er[c8 + 8 * j];
        float4 zv = zr[c8 + 8 * j];
        orow[c8 + 8 * j] = q;
        double d0 = (double)q.x - (double)zv.x;
        double d1 = (double)q.y - (double)zv.y;
        double d2 = (double)q.z - (double)zv.z;
        double d3 = (double)q.w - (double)zv.w;
        lacc += d0 * d0 + d1 * d1 + d2 * d2 + d3 * d3;
    }
    for (int off = 32; off > 0; off >>= 1) lacc += __shfl_down(lacc, off, 64);
    if ((t & 63) == 0) lred[t >> 6] = lacc;
    __syncthreads();
    if (t == 0) partial[blockIdx.x] = lred[0] + lred[1] + lred[2] + lred[3];
}

__global__ void k_finish(const double* __restrict__ partial, float* __restrict__ out, int n) {
    __shared__ double s[256];
    double a = 0.0;
    for (int i = threadIdx.x; i < n; i += 256) a += partial[i];
    s[threadIdx.x] = a;
    __syncthreads();
    for (int off = 128; off > 0; off >>= 1) {
        if (threadIdx.x < off) s[threadIdx.x] += s[threadIdx.x + off];
        __syncthreads();
    }
    if (threadIdx.x == 0)
        out[0] = (float)(1.25 * s[0] / ((double)NROWS * (double)DIM));
}

// ===================== fallback (round-3 validated path) =====================

__global__ __launch_bounds__(256, 1)
void k_main_slow(const float* __restrict__ z, const float* __restrict__ e,
                 const float* __restrict__ Crow, const float* __restrict__ eb2,
                 float* __restrict__ out, double* __restrict__ partial) {
    __shared__ float  zt[64][LSTRIDE];
    __shared__ float  et[64][LSTRIDE];
    __shared__ float  redd[64][17];
    __shared__ int    redi[64][17];
    __shared__ int    bsel[64];
    __shared__ double lred[4];

    const int t  = threadIdx.x;
    const int tx = t & 15;
    const int ty = t >> 4;
    const int row0 = blockIdx.x * 64;

    {
        const float4* zsrc = (const float4*)(z + (size_t)row0 * DIM);
        for (int i = t; i < 64 * (DIM / 4); i += 256) {
            int r = i >> 6, c4 = i & 63;
            *(float4*)&zt[r][c4 * 4] = zsrc[r * (DIM / 4) + c4];
        }
    }
    float Cr[4];
    #pragma unroll
    for (int ri = 0; ri < 4; ++ri) Cr[ri] = Crow[row0 + ty * 4 + ri];
    float bestd[4]; int besti[4];
    #pragma unroll
    for (int ri = 0; ri < 4; ++ri) { bestd[ri] = __int_as_float(0x7f800000); besti[ri] = 0; }

    for (int kt = 0; kt < KCODES / 64; ++kt) {
        __syncthreads();
        {
            const float4* esrc = (const float4*)(e + (size_t)kt * 64 * DIM);
            for (int i = t; i < 64 * (DIM / 4); i += 256) {
                int r = i >> 6, c4 = i & 63;
                *(float4*)&et[r][c4 * 4] = esrc[r * (DIM / 4) + c4];
            }
        }
        __syncthreads();
        double acc[4][4];
        #pragma unroll
        for (int a = 0; a < 4; ++a)
            #pragma unroll
            for (int b = 0; b < 4; ++b) acc[a][b] = 0.0;
        #pragma unroll 4
        for (int d4 = 0; d4 < DIM / 4; ++d4) {
            float4 za[4], ea[4];
            #pragma unroll
            for (int ri = 0; ri < 4; ++ri) za[ri] = *(const float4*)&zt[ty * 4 + ri][d4 * 4];
            #pragma unroll
            for (int ci = 0; ci < 4; ++ci) ea[ci] = *(const float4*)&et[tx + 16 * ci][d4 * 4];
            #pragma unroll
            for (int ri = 0; ri < 4; ++ri)
                #pragma unroll
                for (int ci = 0; ci < 4; ++ci)
                    acc[ri][ci] += (double)za[ri].x * (double)ea[ci].x
                                 + (double)za[ri].y * (double)ea[ci].y
                                 + (double)za[ri].z * (double)ea[ci].z
                                 + (double)za[ri].w * (double)ea[ci].w;
        }
        #pragma unroll
        for (int ci = 0; ci < 4; ++ci) {
            int c = kt * 64 + tx + 16 * ci;
            float ebc = eb2[c];
            #pragma unroll
            for (int ri = 0; ri < 4; ++ri) {
                float d = f32_dist(Cr[ri], ebc, acc[ri][ci]);
                if (d < bestd[ri]) { bestd[ri] = d; besti[ri] = c; }
            }
        }
    }
    __syncthreads();
    #pragma unroll
    for (int ri = 0; ri < 4; ++ri) {
        redd[ty * 4 + ri][tx] = bestd[ri];
        redi[ty * 4 + ri][tx] = besti[ri];
    }
    __syncthreads();
    if (t < 64) {
        float bd = redd[t][0]; int bi = redi[t][0];
        for (int j = 1; j < 16; ++j) {
            float d = redd[t][j]; int i2 = redi[t][j];
            if (d < bd || (d == bd && i2 < bi)) { bd = d; bi = i2; }
        }
        bsel[t] = bi;
        out[1 + (size_t)NROWS * DIM + row0 + t] = (float)bi;
    }
    __syncthreads();
    double lacc = 0.0;
    {
        int r = t >> 2, qd = (t & 3) * 64;
        int bi = bsel[r];
        const float* qrow = e + (size_t)bi * DIM + qd;
        float* orow = out + 1 + (size_t)(row0 + r) * DIM + qd;
        #pragma unroll 4
        for (int d = 0; d < 64; ++d) {
            float qv = qrow[d], zv = zt[r][qd + d];
            double df = (double)qv - (double)zv;
            lacc += df * df;
            orow[d] = qv;
        }
    }
    for (int off = 32; off > 0; off >>= 1) lacc += __shfl_down(lacc, off, 64);
    if ((t & 63) == 0) lred[t >> 6] = lacc;
    __syncthreads();
    if (t == 0) partial[blockIdx.x] = lred[0] + lred[1] + lred[2] + lred[3];
}

// ============================ launch ============================

extern "C" void kernel_launch(void* const* d_in, const int* in_sizes, int n_in,
                              void* d_out, int out_size, void* d_ws, size_t ws_size,
                              hipStream_t stream) {
    const float* z = (const float*)d_in[0];
    const float* e = (const float*)d_in[1];
    float* out = (float*)d_out;
    char* w = (char*)d_ws;

    size_t o = 0;
    auto take = [&](size_t b) { size_t r = o; o = (o + b + 255) & ~(size_t)255; return r; };
    size_t o_zh = take((size_t)NROWS * DIM * 2);
    size_t o_eh = take((size_t)KCODES * DIM * 2);
    size_t o_cr = take((size_t)NROWS * 4);
    size_t o_eb = take((size_t)KCODES * 4);
    size_t o_tk = take((size_t)32 * NROWS * 4);
    size_t o_t2 = take((size_t)32 * NROWS * 4);
    size_t o_fk = take((size_t)NROWS * 8);
    size_t o_cn = take(512);
    size_t o_ls = take((size_t)128 * LCAP * 4);
    size_t o_pt = take((size_t)2048 * 8);
    size_t need = o;

    if (ws_size >= need) {
        ushort* zh = (ushort*)(w + o_zh);
        ushort* eh = (ushort*)(w + o_eh);
        float* Cr  = (float*)(w + o_cr);
        float* eb  = (float*)(w + o_eb);
        float* tk  = (float*)(w + o_tk);
        uint*  tk2 = (uint*)(w + o_t2);
        u64*   fk  = (u64*)(w + o_fk);
        int*   cn  = (int*)(w + o_cn);
        int*   ls  = (int*)(w + o_ls);
        double* pt = (double*)(w + o_pt);

        k_split<<<NROWS * DIM / 8 / 256, 256, 0, stream>>>(z, zh, NROWS * DIM / 8);
        k_split<<<KCODES * DIM / 8 / 256, 256, 0, stream>>>(e, eh, KCODES * DIM / 8);
        k_rownorm<<<NROWS / 256, 256, 0, stream>>>(z, Cr, NROWS);
        k_rownorm<<<KCODES / 256, 256, 0, stream>>>(e, eb, KCODES);
        k_init<<<1, 128, 0, stream>>>(cn);
        k_gemm<<<512, 256, 0, stream>>>(zh, eh, Cr, eb, tk, tk2);
        k_lists<<<NROWS / 256, 256, 0, stream>>>(tk, tk2, cn, ls, fk);
        dim3 ge(128, 16);
        k_exact<<<ge, 256, 0, stream>>>(z, e, Cr, eb, ls, cn, fk);
        k_gather<<<NROWS / 32, 256, 0, stream>>>(z, e, fk, out, pt);
        k_finish<<<1, 256, 0, stream>>>(pt, out, 2048);
    } else {
        float* Cr  = (float*)w;
        float* eb  = Cr + NROWS;
        double* pt = (double*)(eb + KCODES);
        k_rownorm<<<NROWS / 256, 256, 0, stream>>>(z, Cr, NROWS);
        k_rownorm<<<KCODES / 256, 256, 0, stream>>>(e, eb, NROWS >= KCODES ? KCODES : KCODES);
        k_main_slow<<<NROWS / 64, 256, 0, stream>>>(z, e, Cr, eb, out, pt);
        k_finish<<<1, 256, 0, stream>>>(pt, out, NROWS / 64);
    }
}

// Round 10
// 459.791 us; speedup vs baseline: 1.3503x; 1.3503x over previous
//
#include <hip/hip_runtime.h>

#define KCODES 4096
#define DIM    256
#define NROWS  65536
#define MARGIN 4.0e-4f
#define DSLACK 3.0e-5f
#define LCAP   4096
#define LSTRIDE (DIM + 4)

typedef unsigned long long u64;
typedef unsigned int  uint;
typedef unsigned short ushort;
typedef __attribute__((ext_vector_type(8))) short bf16x8;
typedef __attribute__((ext_vector_type(4))) float f32x4;

typedef __attribute__((address_space(3))) uint lds_u32_t;
typedef __attribute__((address_space(1))) uint glb_u32_t;

__device__ __forceinline__ void g2lds16(const void* g, void* l) {
    __builtin_amdgcn_global_load_lds((const glb_u32_t*)g, (lds_u32_t*)l, 16, 0, 0);
}

// cross-lane mins via DPP (VALU pipe, no LDS)
__device__ __forceinline__ float dppmin_quad(float m) {
    m = fminf(m, __int_as_float(__builtin_amdgcn_update_dpp(0, __float_as_int(m), 0xB1, 0xF, 0xF, true)));
    m = fminf(m, __int_as_float(__builtin_amdgcn_update_dpp(0, __float_as_int(m), 0x4E, 0xF, 0xF, true)));
    return m;
}
__device__ __forceinline__ float dppmin_row16(float m) {
    m = fminf(m, __int_as_float(__builtin_amdgcn_update_dpp(0, __float_as_int(m), 0x124, 0xF, 0xF, true)));
    m = fminf(m, __int_as_float(__builtin_amdgcn_update_dpp(0, __float_as_int(m), 0x128, 0xF, 0xF, true)));
    return m;
}
__device__ __forceinline__ uint dppor_row16(uint v) {
    v |= (uint)__builtin_amdgcn_update_dpp(0, (int)v, 0x124, 0xF, 0xF, true);
    v |= (uint)__builtin_amdgcn_update_dpp(0, (int)v, 0x128, 0xF, 0xF, true);
    return v;
}

// ============================ shared helpers ============================

__device__ __forceinline__ float np_half_sum128(const float4* __restrict__ p4) {
    #pragma clang fp contract(off)
    float4 v0 = p4[0], v1 = p4[1];
    float r0 = v0.x * v0.x, r1 = v0.y * v0.y, r2 = v0.z * v0.z, r3 = v0.w * v0.w;
    float r4 = v1.x * v1.x, r5 = v1.y * v1.y, r6 = v1.z * v1.z, r7 = v1.w * v1.w;
    #pragma unroll
    for (int i = 1; i < 16; ++i) {
        float4 a = p4[2 * i], b = p4[2 * i + 1];
        r0 += a.x * a.x; r1 += a.y * a.y; r2 += a.z * a.z; r3 += a.w * a.w;
        r4 += b.x * b.x; r5 += b.y * b.y; r6 += b.z * b.z; r7 += b.w * b.w;
    }
    return ((r0 + r1) + (r2 + r3)) + ((r4 + r5) + (r6 + r7));
}

__global__ void k_rownorm(const float* __restrict__ src, float* __restrict__ dst, int nrows) {
    int r = blockIdx.x * blockDim.x + threadIdx.x;
    if (r >= nrows) return;
    const float4* p4 = (const float4*)(src + (size_t)r * DIM);
    float s;
    {
        #pragma clang fp contract(off)
        s = np_half_sum128(p4) + np_half_sum128(p4 + 32);
    }
    dst[r] = s;
}

// validated (round 3): fl32( fl32(Cr+ebc) - fl32(2*fl32(cross_exact)) )
__device__ __forceinline__ float f32_dist(float Cr, float ebc, double accv) {
    #pragma clang fp contract(off)
    float A = Cr + ebc;
    float B = 2.0f * (float)accv;
    return A - B;
}

__device__ __forceinline__ ushort f2bf(float f) {
    uint u = __float_as_uint(f);
    return (ushort)((u + 0x7fffu + ((u >> 16) & 1u)) >> 16);
}

// ============================ fast-path kernels ============================

__global__ void k_split(const float* __restrict__ src, ushort* __restrict__ dst, int n8) {
    int i = blockIdx.x * blockDim.x + threadIdx.x;
    if (i >= n8) return;
    const float4* s4 = (const float4*)src;
    float4 a = s4[2 * i], b = s4[2 * i + 1];
    uint4 ov;
    ov.x = (uint)f2bf(a.x) | ((uint)f2bf(a.y) << 16);
    ov.y = (uint)f2bf(a.z) | ((uint)f2bf(a.w) << 16);
    ov.z = (uint)f2bf(b.x) | ((uint)f2bf(b.y) << 16);
    ov.w = (uint)f2bf(b.z) | ((uint)f2bf(b.w) << 16);
    *(uint4*)&dst[8 * i] = ov;
}

__global__ void k_init(int* __restrict__ cnt) {
    cnt[threadIdx.x] = 0;
}

// MFMA filter: z in registers (32 rows/wave -> ~160 regs/wave, fits 2 waves/
// SIMD), e streamed as 64-code dbuf swizzled LDS tiles (2x32KB => 2 blocks/CU).
// Each block: 128 rows x all 4096 codes (64 tiles). Grid 512 = 2 blocks/CU.
// tk granularity unchanged: 128-code tiles (pair-merged via mprev) + quad u8.
__global__ __launch_bounds__(256, 2)
void k_gemm(const ushort* __restrict__ zh, const ushort* __restrict__ eh,
            const float* __restrict__ Crow, const float* __restrict__ eb2,
            float* __restrict__ tk, uint* __restrict__ tk2) {
    __shared__ __align__(16) ushort Bs[2][64 * 256];   // 2 x 32KB

    const int t = threadIdx.x;
    const int lane = t & 63;
    const int w = t >> 6;
    const int l15 = lane & 15, l4 = lane >> 4;
    const int row0w = blockIdx.x * 128 + w * 32;

    const char* ebp = (const char*)eh;

    // stage 64-code tile (32KB): linear LDS dest, inverse-swizzled source
    auto stage = [&](int buf, int ct2) {
        const char* base = ebp + (size_t)ct2 * 64 * 512;
        #pragma unroll
        for (int i = 0; i < 8; ++i) {
            int idx = i * 256 + t;            // 0..2047 16B-chunks
            int code = idx >> 5;
            int c16  = idx & 31;
            int src  = (code << 9) + ((c16 ^ (code & 7)) << 4);
            g2lds16(base + src, (char*)Bs[buf] + idx * 16);
        }
    };

    // ---- A: 32 rows x 256 K in registers (MFMA A-frag layout), 64 VGPR ----
    bf16x8 a[2][8];
    #pragma unroll
    for (int f = 0; f < 2; ++f)
        #pragma unroll
        for (int ks = 0; ks < 8; ++ks)
            a[f][ks] = *(const bf16x8*)&zh[(size_t)(row0w + f * 16 + l15) * 256 + ks * 32 + l4 * 8];

    float crf[8];
    #pragma unroll
    for (int f = 0; f < 2; ++f)
        #pragma unroll
        for (int rg = 0; rg < 4; ++rg)
            crf[f * 4 + rg] = Crow[row0w + f * 16 + l4 * 4 + rg];

    float mprev[8];

    stage(0, 0);
    __syncthreads();

    #pragma unroll 2
    for (int ct2 = 0; ct2 < 64; ++ct2) {
        int buf = ct2 & 1;
        if (ct2 < 63) stage(buf ^ 1, ct2 + 1);

        f32x4 acc[2][4];
        #pragma unroll
        for (int f = 0; f < 2; ++f)
            #pragma unroll
            for (int cg = 0; cg < 4; ++cg) acc[f][cg] = (f32x4){0.f, 0.f, 0.f, 0.f};

        const ushort* Bb = Bs[buf];
        #pragma unroll
        for (int ks = 0; ks < 8; ++ks) {
            bf16x8 bfv[4];
            #pragma unroll
            for (int cg = 0; cg < 4; ++cg) {
                int rB = cg * 16 + l15;
                int off = rB * 256 + ((ks * 32 + l4 * 8) ^ ((l15 & 7) << 3));
                bfv[cg] = *(const bf16x8*)&Bb[off];
            }
            #pragma unroll
            for (int f = 0; f < 2; ++f)
                #pragma unroll
                for (int cg = 0; cg < 4; ++cg)
                    acc[f][cg] = __builtin_amdgcn_mfma_f32_16x16x32_bf16(
                        a[f][ks], bfv[cg], acc[f][cg], 0, 0, 0);
        }

        // ---- epilogue: quad-subtile mins; merge tile pairs into 128-code tk ----
        float ebv[4];
        #pragma unroll
        for (int cg = 0; cg < 4; ++cg) ebv[cg] = eb2[ct2 * 64 + cg * 16 + l15];

        #pragma unroll
        for (int f = 0; f < 2; ++f) {
            #pragma unroll
            for (int rg = 0; rg < 4; ++rg) {
                float m;
                {
                    #pragma clang fp contract(off)
                    m = 1e38f;
                    #pragma unroll
                    for (int cg = 0; cg < 4; ++cg) {
                        float A = crf[f * 4 + rg] + ebv[cg];
                        float d = A - 2.0f * acc[f][cg][rg];
                        m = fminf(m, d);
                    }
                }
                m = dppmin_quad(m);              // quad-subtile min (this half)
                if ((ct2 & 1) == 0) {
                    mprev[f * 4 + rg] = m;
                } else {
                    m = fminf(m, mprev[f * 4 + rg]);   // merge 128-code tile
                    float mt = dppmin_row16(m);
                    int q = (int)((m - mt) * 1e5f);
                    q = q > 255 ? 255 : q;
                    uint pk = (uint)q << (8 * (l15 >> 2));
                    pk = dppor_row16(pk);
                    if (l15 == 0) {
                        int grow = row0w + f * 16 + l4 * 4 + rg;
                        int tt = ct2 >> 1;
                        tk [(size_t)tt * NROWS + grow] = mt;
                        tk2[(size_t)tt * NROWS + grow] = pk;
                    }
                }
            }
        }
        __syncthreads();
    }
}

// per row: rowbest over 32 tile-mins; decode subtile mins; staggered sweep +
// wave-aggregated list append; init fkey.
__global__ void k_lists(const float* __restrict__ tk, const uint* __restrict__ tk2,
                        int* __restrict__ cnt, int* __restrict__ list,
                        u64* __restrict__ fkey) {
    int row = blockIdx.x * 256 + threadIdx.x;
    int lane = threadIdx.x & 63;
    float best = __int_as_float(0x7f800000);
    for (int tt = 0; tt < 32; ++tt)
        best = fminf(best, tk[(size_t)tt * NROWS + row]);
    fkey[row] = ~0ull;
    float cutoff = best + (MARGIN + DSLACK);

    int wid = (blockIdx.x << 2) | (threadIdx.x >> 6);
    int off = (wid * 13) & 31;
    for (int g = 0; g < 32; ++g) {
        int tt = (g + off) & 31;
        float tm = tk [(size_t)tt * NROWS + row];
        uint  pk = tk2[(size_t)tt * NROWS + row];
        #pragma unroll
        for (int p = 0; p < 4; ++p) {
            float v = tm + (float)((pk >> (8 * p)) & 255u) * 1e-5f;
            bool pred = v <= cutoff;
            u64 mask = __ballot(pred);
            if (mask) {
                int sub = tt * 4 + p;
                int nq = __popcll(mask);
                int rank = __popcll(mask & ((1ull << lane) - 1ull));
                int base = 0;
                if (lane == 0) base = atomicAdd(&cnt[sub], nq);
                base = __shfl(base, 0, 64);
                int pos = base + rank;
                if (pred && pos < LCAP) list[sub * LCAP + pos] = row;
            }
        }
    }
}

// exact decider; subtile sub = (tile<<2)|quad: codes = tile*128+cg*16+quad*4+r.
// Validated f64-cross + f32_dist + lexicographic (d,idx) key, atomicMin-merged.
__global__ __launch_bounds__(256, 2)
void k_exact(const float* __restrict__ z, const float* __restrict__ e,
             const float* __restrict__ Crow, const float* __restrict__ eb2,
             const int* __restrict__ list, const int* __restrict__ cnt,
             u64* __restrict__ fkey) {
    __shared__ __align__(16) float ex[32][260];
    __shared__ __align__(16) float zx[32][260];
    __shared__ int rows[32];
    __shared__ u64 keytab[32][17];
    const int sub = blockIdx.x;       // 0..127
    const int tile = sub >> 2, qq = sub & 3;
    const int nct = cnt[sub];
    const int t = threadIdx.x;
    const int rp = t & 15, cs = t >> 4;

    {   // stage e subtile (32 quad-mapped codes x 256)
        int cc = t >> 3, c8 = t & 7;
        int gcode = tile * 128 + (cc >> 2) * 16 + qq * 4 + (cc & 3);
        const float4* src = (const float4*)(e + (size_t)gcode * DIM);
        float4* dr = (float4*)ex[cc];
        #pragma unroll
        for (int j = 0; j < 8; ++j) dr[c8 + 8 * j] = src[c8 + 8 * j];
    }
    const int gc0 = tile * 128 + (cs >> 2) * 16 + qq * 4 + (cs & 3);
    const int gc1 = tile * 128 + ((cs >> 2) + 4) * 16 + qq * 4 + (cs & 3);
    const float ebc0 = eb2[gc0];
    const float ebc1 = eb2[gc1];

    for (int base = blockIdx.y * 32; base < nct; base += gridDim.y * 32) {
        __syncthreads();
        if (t < 32) {
            int i = base + t;
            rows[t] = list[sub * LCAP + (i < nct ? i : nct - 1)];
        }
        __syncthreads();
        {
            int rr = t >> 3, c8 = t & 7;
            const float4* src = (const float4*)(z + (size_t)rows[rr] * DIM);
            float4* dr = (float4*)zx[rr];
            #pragma unroll
            for (int j = 0; j < 8; ++j) dr[c8 + 8 * j] = src[c8 + 8 * j];
        }
        __syncthreads();

        double a00 = 0.0, a01 = 0.0, a10 = 0.0, a11 = 0.0;
        const float4* z0 = (const float4*)zx[rp];
        const float4* z1 = (const float4*)zx[rp + 16];
        const float4* e0 = (const float4*)ex[cs];
        const float4* e1 = (const float4*)ex[cs + 16];
        #pragma unroll 8
        for (int d4 = 0; d4 < 64; ++d4) {
            float4 x0 = z0[d4], x1 = z1[d4], y0 = e0[d4], y1 = e1[d4];
            a00 += (double)x0.x * (double)y0.x; a00 += (double)x0.y * (double)y0.y;
            a00 += (double)x0.z * (double)y0.z; a00 += (double)x0.w * (double)y0.w;
            a01 += (double)x0.x * (double)y1.x; a01 += (double)x0.y * (double)y1.y;
            a01 += (double)x0.z * (double)y1.z; a01 += (double)x0.w * (double)y1.w;
            a10 += (double)x1.x * (double)y0.x; a10 += (double)x1.y * (double)y0.y;
            a10 += (double)x1.z * (double)y0.z; a10 += (double)x1.w * (double)y0.w;
            a11 += (double)x1.x * (double)y1.x; a11 += (double)x1.y * (double)y1.y;
            a11 += (double)x1.z * (double)y1.z; a11 += (double)x1.w * (double)y1.w;
        }
        int r0 = rows[rp], r1 = rows[rp + 16];
        float C0 = Crow[r0], C1 = Crow[r1];
        u64 k00 = ((u64)__float_as_uint(f32_dist(C0, ebc0, a00)) << 32) | (u64)gc0;
        u64 k01 = ((u64)__float_as_uint(f32_dist(C0, ebc1, a01)) << 32) | (u64)gc1;
        u64 k10 = ((u64)__float_as_uint(f32_dist(C1, ebc0, a10)) << 32) | (u64)gc0;
        u64 k11 = ((u64)__float_as_uint(f32_dist(C1, ebc1, a11)) << 32) | (u64)gc1;
        keytab[rp][cs]      = k00 < k01 ? k00 : k01;
        keytab[rp + 16][cs] = k10 < k11 ? k10 : k11;
        __syncthreads();
        if (t < 32) {
            u64 kb = keytab[t][0];
            #pragma unroll
            for (int j = 1; j < 16; ++j) {
                u64 k = keytab[t][j];
                kb = k < kb ? k : kb;
            }
            atomicMin((unsigned long long*)&fkey[rows[t]], kb);
        }
    }
}

__global__ __launch_bounds__(256)
void k_gather(const float* __restrict__ z, const float* __restrict__ e,
              const u64* __restrict__ fkey, float* __restrict__ out,
              double* __restrict__ partial) {
    __shared__ double lred[4];
    const int t = threadIdx.x;
    const int row = blockIdx.x * 32 + (t >> 3);
    const int c8 = t & 7;
    const int idx = (int)(fkey[row] & 0xffffffffull);
    if (c8 == 0) out[1 + (size_t)NROWS * DIM + row] = (float)idx;
    const float4* zr = (const float4*)(z + (size_t)row * DIM);
    const float4* er = (const float4*)(e + (size_t)idx * DIM);
    float4* orow = (float4*)(out + 1 + (size_t)row * DIM);
    double lacc = 0.0;
    #pragma unroll
    for (int j = 0; j < 8; ++j) {
        float4 q = er[c8 + 8 * j];
        float4 zv = zr[c8 + 8 * j];
        orow[c8 + 8 * j] = q;
        double d0 = (double)q.x - (double)zv.x;
        double d1 = (double)q.y - (double)zv.y;
        double d2 = (double)q.z - (double)zv.z;
        double d3 = (double)q.w - (double)zv.w;
        lacc += d0 * d0 + d1 * d1 + d2 * d2 + d3 * d3;
    }
    for (int off = 32; off > 0; off >>= 1) lacc += __shfl_down(lacc, off, 64);
    if ((t & 63) == 0) lred[t >> 6] = lacc;
    __syncthreads();
    if (t == 0) partial[blockIdx.x] = lred[0] + lred[1] + lred[2] + lred[3];
}

__global__ void k_finish(const double* __restrict__ partial, float* __restrict__ out, int n) {
    __shared__ double s[256];
    double a = 0.0;
    for (int i = threadIdx.x; i < n; i += 256) a += partial[i];
    s[threadIdx.x] = a;
    __syncthreads();
    for (int off = 128; off > 0; off >>= 1) {
        if (threadIdx.x < off) s[threadIdx.x] += s[threadIdx.x + off];
        __syncthreads();
    }
    if (threadIdx.x == 0)
        out[0] = (float)(1.25 * s[0] / ((double)NROWS * (double)DIM));
}

// ===================== fallback (round-3 validated path) =====================

__global__ __launch_bounds__(256, 1)
void k_main_slow(const float* __restrict__ z, const float* __restrict__ e,
                 const float* __restrict__ Crow, const float* __restrict__ eb2,
                 float* __restrict__ out, double* __restrict__ partial) {
    __shared__ float  zt[64][LSTRIDE];
    __shared__ float  et[64][LSTRIDE];
    __shared__ float  redd[64][17];
    __shared__ int    redi[64][17];
    __shared__ int    bsel[64];
    __shared__ double lred[4];

    const int t  = threadIdx.x;
    const int tx = t & 15;
    const int ty = t >> 4;
    const int row0 = blockIdx.x * 64;

    {
        const float4* zsrc = (const float4*)(z + (size_t)row0 * DIM);
        for (int i = t; i < 64 * (DIM / 4); i += 256) {
            int r = i >> 6, c4 = i & 63;
            *(float4*)&zt[r][c4 * 4] = zsrc[r * (DIM / 4) + c4];
        }
    }
    float Cr[4];
    #pragma unroll
    for (int ri = 0; ri < 4; ++ri) Cr[ri] = Crow[row0 + ty * 4 + ri];
    float bestd[4]; int besti[4];
    #pragma unroll
    for (int ri = 0; ri < 4; ++ri) { bestd[ri] = __int_as_float(0x7f800000); besti[ri] = 0; }

    for (int kt = 0; kt < KCODES / 64; ++kt) {
        __syncthreads();
        {
            const float4* esrc = (const float4*)(e + (size_t)kt * 64 * DIM);
            for (int i = t; i < 64 * (DIM / 4); i += 256) {
                int r = i >> 6, c4 = i & 63;
                *(float4*)&et[r][c4 * 4] = esrc[r * (DIM / 4) + c4];
            }
        }
        __syncthreads();
        double acc[4][4];
        #pragma unroll
        for (int a = 0; a < 4; ++a)
            #pragma unroll
            for (int b = 0; b < 4; ++b) acc[a][b] = 0.0;
        #pragma unroll 4
        for (int d4 = 0; d4 < DIM / 4; ++d4) {
            float4 za[4], ea[4];
            #pragma unroll
            for (int ri = 0; ri < 4; ++ri) za[ri] = *(const float4*)&zt[ty * 4 + ri][d4 * 4];
            #pragma unroll
            for (int ci = 0; ci < 4; ++ci) ea[ci] = *(const float4*)&et[tx + 16 * ci][d4 * 4];
            #pragma unroll
            for (int ri = 0; ri < 4; ++ri)
                #pragma unroll
                for (int ci = 0; ci < 4; ++ci)
                    acc[ri][ci] += (double)za[ri].x * (double)ea[ci].x
                                 + (double)za[ri].y * (double)ea[ci].y
                                 + (double)za[ri].z * (double)ea[ci].z
                                 + (double)za[ri].w * (double)ea[ci].w;
        }
        #pragma unroll
        for (int ci = 0; ci < 4; ++ci) {
            int c = kt * 64 + tx + 16 * ci;
            float ebc = eb2[c];
            #pragma unroll
            for (int ri = 0; ri < 4; ++ri) {
                float d = f32_dist(Cr[ri], ebc, acc[ri][ci]);
                if (d < bestd[ri]) { bestd[ri] = d; besti[ri] = c; }
            }
        }
    }
    __syncthreads();
    #pragma unroll
    for (int ri = 0; ri < 4; ++ri) {
        redd[ty * 4 + ri][tx] = bestd[ri];
        redi[ty * 4 + ri][tx] = besti[ri];
    }
    __syncthreads();
    if (t < 64) {
        float bd = redd[t][0]; int bi = redi[t][0];
        for (int j = 1; j < 16; ++j) {
            float d = redd[t][j]; int i2 = redi[t][j];
            if (d < bd || (d == bd && i2 < bi)) { bd = d; bi = i2; }
        }
        bsel[t] = bi;
        out[1 + (size_t)NROWS * DIM + row0 + t] = (float)bi;
    }
    __syncthreads();
    double lacc = 0.0;
    {
        int r = t >> 2, qd = (t & 3) * 64;
        int bi = bsel[r];
        const float* qrow = e + (size_t)bi * DIM + qd;
        float* orow = out + 1 + (size_t)(row0 + r) * DIM + qd;
        #pragma unroll 4
        for (int d = 0; d < 64; ++d) {
            float qv = qrow[d], zv = zt[r][qd + d];
            double df = (double)qv - (double)zv;
            lacc += df * df;
            orow[d] = qv;
        }
    }
    for (int off = 32; off > 0; off >>= 1) lacc += __shfl_down(lacc, off, 64);
    if ((t & 63) == 0) lred[t >> 6] = lacc;
    __syncthreads();
    if (t == 0) partial[blockIdx.x] = lred[0] + lred[1] + lred[2] + lred[3];
}

// ============================ launch ============================

extern "C" void kernel_launch(void* const* d_in, const int* in_sizes, int n_in,
                              void* d_out, int out_size, void* d_ws, size_t ws_size,
                              hipStream_t stream) {
    const float* z = (const float*)d_in[0];
    const float* e = (const float*)d_in[1];
    float* out = (float*)d_out;
    char* w = (char*)d_ws;

    size_t o = 0;
    auto take = [&](size_t b) { size_t r = o; o = (o + b + 255) & ~(size_t)255; return r; };
    size_t o_zh = take((size_t)NROWS * DIM * 2);
    size_t o_eh = take((size_t)KCODES * DIM * 2);
    size_t o_cr = take((size_t)NROWS * 4);
    size_t o_eb = take((size_t)KCODES * 4);
    size_t o_tk = take((size_t)32 * NROWS * 4);
    size_t o_t2 = take((size_t)32 * NROWS * 4);
    size_t o_fk = take((size_t)NROWS * 8);
    size_t o_cn = take(512);
    size_t o_ls = take((size_t)128 * LCAP * 4);
    size_t o_pt = take((size_t)2048 * 8);
    size_t need = o;

    if (ws_size >= need) {
        ushort* zh = (ushort*)(w + o_zh);
        ushort* eh = (ushort*)(w + o_eh);
        float* Cr  = (float*)(w + o_cr);
        float* eb  = (float*)(w + o_eb);
        float* tk  = (float*)(w + o_tk);
        uint*  tk2 = (uint*)(w + o_t2);
        u64*   fk  = (u64*)(w + o_fk);
        int*   cn  = (int*)(w + o_cn);
        int*   ls  = (int*)(w + o_ls);
        double* pt = (double*)(w + o_pt);

        k_split<<<NROWS * DIM / 8 / 256, 256, 0, stream>>>(z, zh, NROWS * DIM / 8);
        k_split<<<KCODES * DIM / 8 / 256, 256, 0, stream>>>(e, eh, KCODES * DIM / 8);
        k_rownorm<<<NROWS / 256, 256, 0, stream>>>(z, Cr, NROWS);
        k_rownorm<<<KCODES / 256, 256, 0, stream>>>(e, eb, KCODES);
        k_init<<<1, 128, 0, stream>>>(cn);
        k_gemm<<<NROWS / 128, 256, 0, stream>>>(zh, eh, Cr, eb, tk, tk2);
        k_lists<<<NROWS / 256, 256, 0, stream>>>(tk, tk2, cn, ls, fk);
        dim3 ge(128, 16);
        k_exact<<<ge, 256, 0, stream>>>(z, e, Cr, eb, ls, cn, fk);
        k_gather<<<NROWS / 32, 256, 0, stream>>>(z, e, fk, out, pt);
        k_finish<<<1, 256, 0, stream>>>(pt, out, 2048);
    } else {
        float* Cr  = (float*)w;
        float* eb  = Cr + NROWS;
        double* pt = (double*)(eb + KCODES);
        k_rownorm<<<NROWS / 256, 256, 0, stream>>>(z, Cr, NROWS);
        k_rownorm<<<KCODES / 256, 256, 0, stream>>>(e, eb, KCODES);
        k_main_slow<<<NROWS / 64, 256, 0, stream>>>(z, e, Cr, eb, out, pt);
        k_finish<<<1, 256, 0, stream>>>(pt, out, NROWS / 64);
    }
}

// Round 11
// 344.672 us; speedup vs baseline: 1.8012x; 1.3340x over previous
//
#include <hip/hip_runtime.h>

#define KCODES 4096
#define DIM    256
#define NROWS  65536
#define MARGIN 4.0e-4f
#define DSLACK 3.0e-5f
#define LCAP   4096
#define CPAD   32          // ints between counters: 128B = 1 L2 line each
#define LSTRIDE (DIM + 4)

typedef unsigned long long u64;
typedef unsigned int  uint;
typedef unsigned short ushort;
typedef __attribute__((ext_vector_type(8))) short bf16x8;
typedef __attribute__((ext_vector_type(4))) float f32x4;

typedef __attribute__((address_space(3))) uint lds_u32_t;
typedef __attribute__((address_space(1))) uint glb_u32_t;

__device__ __forceinline__ void g2lds16(const void* g, void* l) {
    __builtin_amdgcn_global_load_lds((const glb_u32_t*)g, (lds_u32_t*)l, 16, 0, 0);
}

// cross-lane mins via DPP (VALU pipe, no LDS)
__device__ __forceinline__ float dppmin_quad(float m) {
    m = fminf(m, __int_as_float(__builtin_amdgcn_update_dpp(0, __float_as_int(m), 0xB1, 0xF, 0xF, true)));
    m = fminf(m, __int_as_float(__builtin_amdgcn_update_dpp(0, __float_as_int(m), 0x4E, 0xF, 0xF, true)));
    return m;
}
__device__ __forceinline__ float dppmin_row16(float m) {
    m = fminf(m, __int_as_float(__builtin_amdgcn_update_dpp(0, __float_as_int(m), 0x124, 0xF, 0xF, true)));
    m = fminf(m, __int_as_float(__builtin_amdgcn_update_dpp(0, __float_as_int(m), 0x128, 0xF, 0xF, true)));
    return m;
}
__device__ __forceinline__ uint dppor_row16(uint v) {
    v |= (uint)__builtin_amdgcn_update_dpp(0, (int)v, 0x124, 0xF, 0xF, true);
    v |= (uint)__builtin_amdgcn_update_dpp(0, (int)v, 0x128, 0xF, 0xF, true);
    return v;
}

// ============================ shared helpers ============================

__device__ __forceinline__ float np_half_sum128(const float4* __restrict__ p4) {
    #pragma clang fp contract(off)
    float4 v0 = p4[0], v1 = p4[1];
    float r0 = v0.x * v0.x, r1 = v0.y * v0.y, r2 = v0.z * v0.z, r3 = v0.w * v0.w;
    float r4 = v1.x * v1.x, r5 = v1.y * v1.y, r6 = v1.z * v1.z, r7 = v1.w * v1.w;
    #pragma unroll
    for (int i = 1; i < 16; ++i) {
        float4 a = p4[2 * i], b = p4[2 * i + 1];
        r0 += a.x * a.x; r1 += a.y * a.y; r2 += a.z * a.z; r3 += a.w * a.w;
        r4 += b.x * b.x; r5 += b.y * b.y; r6 += b.z * b.z; r7 += b.w * b.w;
    }
    return ((r0 + r1) + (r2 + r3)) + ((r4 + r5) + (r6 + r7));
}

__global__ void k_rownorm(const float* __restrict__ src, float* __restrict__ dst, int nrows) {
    int r = blockIdx.x * blockDim.x + threadIdx.x;
    if (r >= nrows) return;
    const float4* p4 = (const float4*)(src + (size_t)r * DIM);
    float s;
    {
        #pragma clang fp contract(off)
        s = np_half_sum128(p4) + np_half_sum128(p4 + 32);
    }
    dst[r] = s;
}

// validated (round 3): fl32( fl32(Cr+ebc) - fl32(2*fl32(cross_exact)) )
__device__ __forceinline__ float f32_dist(float Cr, float ebc, double accv) {
    #pragma clang fp contract(off)
    float A = Cr + ebc;
    float B = 2.0f * (float)accv;
    return A - B;
}

__device__ __forceinline__ ushort f2bf(float f) {
    uint u = __float_as_uint(f);
    return (ushort)((u + 0x7fffu + ((u >> 16) & 1u)) >> 16);
}

// ============================ fast-path kernels ============================

__global__ void k_split(const float* __restrict__ src, ushort* __restrict__ dst, int n8) {
    int i = blockIdx.x * blockDim.x + threadIdx.x;
    if (i >= n8) return;
    const float4* s4 = (const float4*)src;
    float4 a = s4[2 * i], b = s4[2 * i + 1];
    uint4 ov;
    ov.x = (uint)f2bf(a.x) | ((uint)f2bf(a.y) << 16);
    ov.y = (uint)f2bf(a.z) | ((uint)f2bf(a.w) << 16);
    ov.z = (uint)f2bf(b.x) | ((uint)f2bf(b.y) << 16);
    ov.w = (uint)f2bf(b.z) | ((uint)f2bf(b.w) << 16);
    *(uint4*)&dst[8 * i] = ov;
}

__global__ void k_init(int* __restrict__ cnt) {
    cnt[blockIdx.x * 256 + threadIdx.x] = 0;
}

// MFMA filter: z in registers (32 rows/wave), e streamed as 64-code dbuf
// swizzled LDS tiles (2x32KB => 2 blocks/CU, 2 waves/SIMD). Each block:
// 128 rows x all 4096 codes. tk granularity: 128-code tiles (pair-merged
// via mprev) + quad-subtile u8 deltas.
__global__ __launch_bounds__(256, 2)
void k_gemm(const ushort* __restrict__ zh, const ushort* __restrict__ eh,
            const float* __restrict__ Crow, const float* __restrict__ eb2,
            float* __restrict__ tk, uint* __restrict__ tk2) {
    __shared__ __align__(16) ushort Bs[2][64 * 256];   // 2 x 32KB

    const int t = threadIdx.x;
    const int lane = t & 63;
    const int w = t >> 6;
    const int l15 = lane & 15, l4 = lane >> 4;
    const int row0w = blockIdx.x * 128 + w * 32;

    const char* ebp = (const char*)eh;

    auto stage = [&](int buf, int ct2) {
        const char* base = ebp + (size_t)ct2 * 64 * 512;
        #pragma unroll
        for (int i = 0; i < 8; ++i) {
            int idx = i * 256 + t;            // 0..2047 16B-chunks
            int code = idx >> 5;
            int c16  = idx & 31;
            int src  = (code << 9) + ((c16 ^ (code & 7)) << 4);
            g2lds16(base + src, (char*)Bs[buf] + idx * 16);
        }
    };

    // ---- A: 32 rows x 256 K in registers (MFMA A-frag layout), 64 VGPR ----
    bf16x8 a[2][8];
    #pragma unroll
    for (int f = 0; f < 2; ++f)
        #pragma unroll
        for (int ks = 0; ks < 8; ++ks)
            a[f][ks] = *(const bf16x8*)&zh[(size_t)(row0w + f * 16 + l15) * 256 + ks * 32 + l4 * 8];

    float crf[8];
    #pragma unroll
    for (int f = 0; f < 2; ++f)
        #pragma unroll
        for (int rg = 0; rg < 4; ++rg)
            crf[f * 4 + rg] = Crow[row0w + f * 16 + l4 * 4 + rg];

    float mprev[8];

    stage(0, 0);
    __syncthreads();

    #pragma unroll 2
    for (int ct2 = 0; ct2 < 64; ++ct2) {
        int buf = ct2 & 1;
        if (ct2 < 63) stage(buf ^ 1, ct2 + 1);

        f32x4 acc[2][4];
        #pragma unroll
        for (int f = 0; f < 2; ++f)
            #pragma unroll
            for (int cg = 0; cg < 4; ++cg) acc[f][cg] = (f32x4){0.f, 0.f, 0.f, 0.f};

        const ushort* Bb = Bs[buf];
        #pragma unroll
        for (int ks = 0; ks < 8; ++ks) {
            bf16x8 bfv[4];
            #pragma unroll
            for (int cg = 0; cg < 4; ++cg) {
                int rB = cg * 16 + l15;
                int off = rB * 256 + ((ks * 32 + l4 * 8) ^ ((l15 & 7) << 3));
                bfv[cg] = *(const bf16x8*)&Bb[off];
            }
            #pragma unroll
            for (int f = 0; f < 2; ++f)
                #pragma unroll
                for (int cg = 0; cg < 4; ++cg)
                    acc[f][cg] = __builtin_amdgcn_mfma_f32_16x16x32_bf16(
                        a[f][ks], bfv[cg], acc[f][cg], 0, 0, 0);
        }

        // ---- epilogue: quad-subtile mins; merge tile pairs into 128-code tk ----
        float ebv[4];
        #pragma unroll
        for (int cg = 0; cg < 4; ++cg) ebv[cg] = eb2[ct2 * 64 + cg * 16 + l15];

        #pragma unroll
        for (int f = 0; f < 2; ++f) {
            #pragma unroll
            for (int rg = 0; rg < 4; ++rg) {
                float m;
                {
                    #pragma clang fp contract(off)
                    m = 1e38f;
                    #pragma unroll
                    for (int cg = 0; cg < 4; ++cg) {
                        float A = crf[f * 4 + rg] + ebv[cg];
                        float d = A - 2.0f * acc[f][cg][rg];
                        m = fminf(m, d);
                    }
                }
                m = dppmin_quad(m);              // quad-subtile min (this half)
                if ((ct2 & 1) == 0) {
                    mprev[f * 4 + rg] = m;
                } else {
                    m = fminf(m, mprev[f * 4 + rg]);   // merge 128-code tile
                    float mt = dppmin_row16(m);
                    int q = (int)((m - mt) * 1e5f);
                    q = q > 255 ? 255 : q;
                    uint pk = (uint)q << (8 * (l15 >> 2));
                    pk = dppor_row16(pk);
                    if (l15 == 0) {
                        int grow = row0w + f * 16 + l4 * 4 + rg;
                        int tt = ct2 >> 1;
                        tk [(size_t)tt * NROWS + grow] = mt;
                        tk2[(size_t)tt * NROWS + grow] = pk;
                    }
                }
            }
        }
        __syncthreads();
    }
}

// per row: rowbest over 32 tile-mins; decode subtile mins; wave-aggregated
// append to per-subtile lists. Full unroll => tm/pk in registers (static
// indices only); counters padded to 1 L2 line each (atomic line-serialization
// was the 167us cost). init fkey here.
__global__ void k_lists(const float* __restrict__ tk, const uint* __restrict__ tk2,
                        int* __restrict__ cnt, int* __restrict__ list,
                        u64* __restrict__ fkey) {
    int row = blockIdx.x * 256 + threadIdx.x;
    int lane = threadIdx.x & 63;
    float tm[32]; uint pk[32];
    #pragma unroll
    for (int tt = 0; tt < 32; ++tt) {
        tm[tt] = tk [(size_t)tt * NROWS + row];
        pk[tt] = tk2[(size_t)tt * NROWS + row];
    }
    float best = tm[0];
    #pragma unroll
    for (int tt = 1; tt < 32; ++tt) best = fminf(best, tm[tt]);
    fkey[row] = ~0ull;
    float cutoff = best + (MARGIN + DSLACK);

    #pragma unroll
    for (int tt = 0; tt < 32; ++tt) {
        #pragma unroll
        for (int p = 0; p < 4; ++p) {
            float v = tm[tt] + (float)((pk[tt] >> (8 * p)) & 255u) * 1e-5f;
            bool pred = v <= cutoff;
            u64 mask = __ballot(pred);
            if (mask) {
                int sub = tt * 4 + p;
                int nq = __popcll(mask);
                int rank = __popcll(mask & ((1ull << lane) - 1ull));
                int base = 0;
                if (lane == 0) base = atomicAdd(&cnt[sub * CPAD], nq);
                base = __shfl(base, 0, 64);
                int pos = base + rank;
                if (pred && pos < LCAP) list[sub * LCAP + pos] = row;
            }
        }
    }
}

// exact decider; subtile sub = (tile<<2)|quad: codes = tile*128+cg*16+quad*4+r.
// Validated f64-cross + f32_dist + lexicographic (d,idx) key, atomicMin-merged.
__global__ __launch_bounds__(256, 2)
void k_exact(const float* __restrict__ z, const float* __restrict__ e,
             const float* __restrict__ Crow, const float* __restrict__ eb2,
             const int* __restrict__ list, const int* __restrict__ cnt,
             u64* __restrict__ fkey) {
    __shared__ __align__(16) float ex[32][260];
    __shared__ __align__(16) float zx[32][260];
    __shared__ int rows[32];
    __shared__ u64 keytab[32][17];
    const int sub = blockIdx.x;       // 0..127
    const int tile = sub >> 2, qq = sub & 3;
    const int nct = cnt[sub * CPAD];
    const int t = threadIdx.x;
    const int rp = t & 15, cs = t >> 4;

    {   // stage e subtile (32 quad-mapped codes x 256)
        int cc = t >> 3, c8 = t & 7;
        int gcode = tile * 128 + (cc >> 2) * 16 + qq * 4 + (cc & 3);
        const float4* src = (const float4*)(e + (size_t)gcode * DIM);
        float4* dr = (float4*)ex[cc];
        #pragma unroll
        for (int j = 0; j < 8; ++j) dr[c8 + 8 * j] = src[c8 + 8 * j];
    }
    const int gc0 = tile * 128 + (cs >> 2) * 16 + qq * 4 + (cs & 3);
    const int gc1 = tile * 128 + ((cs >> 2) + 4) * 16 + qq * 4 + (cs & 3);
    const float ebc0 = eb2[gc0];
    const float ebc1 = eb2[gc1];

    for (int base = blockIdx.y * 32; base < nct; base += gridDim.y * 32) {
        __syncthreads();
        if (t < 32) {
            int i = base + t;
            rows[t] = list[sub * LCAP + (i < nct ? i : nct - 1)];
        }
        __syncthreads();
        {
            int rr = t >> 3, c8 = t & 7;
            const float4* src = (const float4*)(z + (size_t)rows[rr] * DIM);
            float4* dr = (float4*)zx[rr];
            #pragma unroll
            for (int j = 0; j < 8; ++j) dr[c8 + 8 * j] = src[c8 + 8 * j];
        }
        __syncthreads();

        double a00 = 0.0, a01 = 0.0, a10 = 0.0, a11 = 0.0;
        const float4* z0 = (const float4*)zx[rp];
        const float4* z1 = (const float4*)zx[rp + 16];
        const float4* e0 = (const float4*)ex[cs];
        const float4* e1 = (const float4*)ex[cs + 16];
        #pragma unroll 8
        for (int d4 = 0; d4 < 64; ++d4) {
            float4 x0 = z0[d4], x1 = z1[d4], y0 = e0[d4], y1 = e1[d4];
            a00 += (double)x0.x * (double)y0.x; a00 += (double)x0.y * (double)y0.y;
            a00 += (double)x0.z * (double)y0.z; a00 += (double)x0.w * (double)y0.w;
            a01 += (double)x0.x * (double)y1.x; a01 += (double)x0.y * (double)y1.y;
            a01 += (double)x0.z * (double)y1.z; a01 += (double)x0.w * (double)y1.w;
            a10 += (double)x1.x * (double)y0.x; a10 += (double)x1.y * (double)y0.y;
            a10 += (double)x1.z * (double)y0.z; a10 += (double)x1.w * (double)y0.w;
            a11 += (double)x1.x * (double)y1.x; a11 += (double)x1.y * (double)y1.y;
            a11 += (double)x1.z * (double)y1.z; a11 += (double)x1.w * (double)y1.w;
        }
        int r0 = rows[rp], r1 = rows[rp + 16];
        float C0 = Crow[r0], C1 = Crow[r1];
        u64 k00 = ((u64)__float_as_uint(f32_dist(C0, ebc0, a00)) << 32) | (u64)gc0;
        u64 k01 = ((u64)__float_as_uint(f32_dist(C0, ebc1, a01)) << 32) | (u64)gc1;
        u64 k10 = ((u64)__float_as_uint(f32_dist(C1, ebc0, a10)) << 32) | (u64)gc0;
        u64 k11 = ((u64)__float_as_uint(f32_dist(C1, ebc1, a11)) << 32) | (u64)gc1;
        keytab[rp][cs]      = k00 < k01 ? k00 : k01;
        keytab[rp + 16][cs] = k10 < k11 ? k10 : k11;
        __syncthreads();
        if (t < 32) {
            u64 kb = keytab[t][0];
            #pragma unroll
            for (int j = 1; j < 16; ++j) {
                u64 k = keytab[t][j];
                kb = k < kb ? k : kb;
            }
            atomicMin((unsigned long long*)&fkey[rows[t]], kb);
        }
    }
}

__global__ __launch_bounds__(256)
void k_gather(const float* __restrict__ z, const float* __restrict__ e,
              const u64* __restrict__ fkey, float* __restrict__ out,
              double* __restrict__ partial) {
    __shared__ double lred[4];
    const int t = threadIdx.x;
    const int row = blockIdx.x * 32 + (t >> 3);
    const int c8 = t & 7;
    const int idx = (int)(fkey[row] & 0xffffffffull);
    if (c8 == 0) out[1 + (size_t)NROWS * DIM + row] = (float)idx;
    const float4* zr = (const float4*)(z + (size_t)row * DIM);
    const float4* er = (const float4*)(e + (size_t)idx * DIM);
    float4* orow = (float4*)(out + 1 + (size_t)row * DIM);
    double lacc = 0.0;
    #pragma unroll
    for (int j = 0; j < 8; ++j) {
        float4 q = er[c8 + 8 * j];
        float4 zv = zr[c8 + 8 * j];
        orow[c8 + 8 * j] = q;
        double d0 = (double)q.x - (double)zv.x;
        double d1 = (double)q.y - (double)zv.y;
        double d2 = (double)q.z - (double)zv.z;
        double d3 = (double)q.w - (double)zv.w;
        lacc += d0 * d0 + d1 * d1 + d2 * d2 + d3 * d3;
    }
    for (int off = 32; off > 0; off >>= 1) lacc += __shfl_down(lacc, off, 64);
    if ((t & 63) == 0) lred[t >> 6] = lacc;
    __syncthreads();
    if (t == 0) partial[blockIdx.x] = lred[0] + lred[1] + lred[2] + lred[3];
}

__global__ void k_finish(const double* __restrict__ partial, float* __restrict__ out, int n) {
    __shared__ double s[256];
    double a = 0.0;
    for (int i = threadIdx.x; i < n; i += 256) a += partial[i];
    s[threadIdx.x] = a;
    __syncthreads();
    for (int off = 128; off > 0; off >>= 1) {
        if (threadIdx.x < off) s[threadIdx.x] += s[threadIdx.x + off];
        __syncthreads();
    }
    if (threadIdx.x == 0)
        out[0] = (float)(1.25 * s[0] / ((double)NROWS * (double)DIM));
}

// ===================== fallback (round-3 validated path) =====================

__global__ __launch_bounds__(256, 1)
void k_main_slow(const float* __restrict__ z, const float* __restrict__ e,
                 const float* __restrict__ Crow, const float* __restrict__ eb2,
                 float* __restrict__ out, double* __restrict__ partial) {
    __shared__ float  zt[64][LSTRIDE];
    __shared__ float  et[64][LSTRIDE];
    __shared__ float  redd[64][17];
    __shared__ int    redi[64][17];
    __shared__ int    bsel[64];
    __shared__ double lred[4];

    const int t  = threadIdx.x;
    const int tx = t & 15;
    const int ty = t >> 4;
    const int row0 = blockIdx.x * 64;

    {
        const float4* zsrc = (const float4*)(z + (size_t)row0 * DIM);
        for (int i = t; i < 64 * (DIM / 4); i += 256) {
            int r = i >> 6, c4 = i & 63;
            *(float4*)&zt[r][c4 * 4] = zsrc[r * (DIM / 4) + c4];
        }
    }
    float Cr[4];
    #pragma unroll
    for (int ri = 0; ri < 4; ++ri) Cr[ri] = Crow[row0 + ty * 4 + ri];
    float bestd[4]; int besti[4];
    #pragma unroll
    for (int ri = 0; ri < 4; ++ri) { bestd[ri] = __int_as_float(0x7f800000); besti[ri] = 0; }

    for (int kt = 0; kt < KCODES / 64; ++kt) {
        __syncthreads();
        {
            const float4* esrc = (const float4*)(e + (size_t)kt * 64 * DIM);
            for (int i = t; i < 64 * (DIM / 4); i += 256) {
                int r = i >> 6, c4 = i & 63;
                *(float4*)&et[r][c4 * 4] = esrc[r * (DIM / 4) + c4];
            }
        }
        __syncthreads();
        double acc[4][4];
        #pragma unroll
        for (int a = 0; a < 4; ++a)
            #pragma unroll
            for (int b = 0; b < 4; ++b) acc[a][b] = 0.0;
        #pragma unroll 4
        for (int d4 = 0; d4 < DIM / 4; ++d4) {
            float4 za[4], ea[4];
            #pragma unroll
            for (int ri = 0; ri < 4; ++ri) za[ri] = *(const float4*)&zt[ty * 4 + ri][d4 * 4];
            #pragma unroll
            for (int ci = 0; ci < 4; ++ci) ea[ci] = *(const float4*)&et[tx + 16 * ci][d4 * 4];
            #pragma unroll
            for (int ri = 0; ri < 4; ++ri)
                #pragma unroll
                for (int ci = 0; ci < 4; ++ci)
                    acc[ri][ci] += (double)za[ri].x * (double)ea[ci].x
                                 + (double)za[ri].y * (double)ea[ci].y
                                 + (double)za[ri].z * (double)ea[ci].z
                                 + (double)za[ri].w * (double)ea[ci].w;
        }
        #pragma unroll
        for (int ci = 0; ci < 4; ++ci) {
            int c = kt * 64 + tx + 16 * ci;
            float ebc = eb2[c];
            #pragma unroll
            for (int ri = 0; ri < 4; ++ri) {
                float d = f32_dist(Cr[ri], ebc, acc[ri][ci]);
                if (d < bestd[ri]) { bestd[ri] = d; besti[ri] = c; }
            }
        }
    }
    __syncthreads();
    #pragma unroll
    for (int ri = 0; ri < 4; ++ri) {
        redd[ty * 4 + ri][tx] = bestd[ri];
        redi[ty * 4 + ri][tx] = besti[ri];
    }
    __syncthreads();
    if (t < 64) {
        float bd = redd[t][0]; int bi = redi[t][0];
        for (int j = 1; j < 16; ++j) {
            float d = redd[t][j]; int i2 = redi[t][j];
            if (d < bd || (d == bd && i2 < bi)) { bd = d; bi = i2; }
        }
        bsel[t] = bi;
        out[1 + (size_t)NROWS * DIM + row0 + t] = (float)bi;
    }
    __syncthreads();
    double lacc = 0.0;
    {
        int r = t >> 2, qd = (t & 3) * 64;
        int bi = bsel[r];
        const float* qrow = e + (size_t)bi * DIM + qd;
        float* orow = out + 1 + (size_t)(row0 + r) * DIM + qd;
        #pragma unroll 4
        for (int d = 0; d < 64; ++d) {
            float qv = qrow[d], zv = zt[r][qd + d];
            double df = (double)qv - (double)zv;
            lacc += df * df;
            orow[d] = qv;
        }
    }
    for (int off = 32; off > 0; off >>= 1) lacc += __shfl_down(lacc, off, 64);
    if ((t & 63) == 0) lred[t >> 6] = lacc;
    __syncthreads();
    if (t == 0) partial[blockIdx.x] = lred[0] + lred[1] + lred[2] + lred[3];
}

// ============================ launch ============================

extern "C" void kernel_launch(void* const* d_in, const int* in_sizes, int n_in,
                              void* d_out, int out_size, void* d_ws, size_t ws_size,
                              hipStream_t stream) {
    const float* z = (const float*)d_in[0];
    const float* e = (const float*)d_in[1];
    float* out = (float*)d_out;
    char* w = (char*)d_ws;

    size_t o = 0;
    auto take = [&](size_t b) { size_t r = o; o = (o + b + 255) & ~(size_t)255; return r; };
    size_t o_zh = take((size_t)NROWS * DIM * 2);
    size_t o_eh = take((size_t)KCODES * DIM * 2);
    size_t o_cr = take((size_t)NROWS * 4);
    size_t o_eb = take((size_t)KCODES * 4);
    size_t o_tk = take((size_t)32 * NROWS * 4);
    size_t o_t2 = take((size_t)32 * NROWS * 4);
    size_t o_fk = take((size_t)NROWS * 8);
    size_t o_cn = take((size_t)128 * CPAD * 4);
    size_t o_ls = take((size_t)128 * LCAP * 4);
    size_t o_pt = take((size_t)2048 * 8);
    size_t need = o;

    if (ws_size >= need) {
        ushort* zh = (ushort*)(w + o_zh);
        ushort* eh = (ushort*)(w + o_eh);
        float* Cr  = (float*)(w + o_cr);
        float* eb  = (float*)(w + o_eb);
        float* tk  = (float*)(w + o_tk);
        uint*  tk2 = (uint*)(w + o_t2);
        u64*   fk  = (u64*)(w + o_fk);
        int*   cn  = (int*)(w + o_cn);
        int*   ls  = (int*)(w + o_ls);
        double* pt = (double*)(w + o_pt);

        k_split<<<NROWS * DIM / 8 / 256, 256, 0, stream>>>(z, zh, NROWS * DIM / 8);
        k_split<<<KCODES * DIM / 8 / 256, 256, 0, stream>>>(e, eh, KCODES * DIM / 8);
        k_rownorm<<<NROWS / 256, 256, 0, stream>>>(z, Cr, NROWS);
        k_rownorm<<<KCODES / 256, 256, 0, stream>>>(e, eb, KCODES);
        k_init<<<(128 * CPAD) / 256, 256, 0, stream>>>(cn);
        k_gemm<<<NROWS / 128, 256, 0, stream>>>(zh, eh, Cr, eb, tk, tk2);
        k_lists<<<NROWS / 256, 256, 0, stream>>>(tk, tk2, cn, ls, fk);
        dim3 ge(128, 16);
        k_exact<<<ge, 256, 0, stream>>>(z, e, Cr, eb, ls, cn, fk);
        k_gather<<<NROWS / 32, 256, 0, stream>>>(z, e, fk, out, pt);
        k_finish<<<1, 256, 0, stream>>>(pt, out, 2048);
    } else {
        float* Cr  = (float*)w;
        float* eb  = Cr + NROWS;
        double* pt = (double*)(eb + KCODES);
        k_rownorm<<<NROWS / 256, 256, 0, stream>>>(z, Cr, NROWS);
        k_rownorm<<<KCODES / 256, 256, 0, stream>>>(e, eb, KCODES);
        k_main_slow<<<NROWS / 64, 256, 0, stream>>>(z, e, Cr, eb, out, pt);
        k_finish<<<1, 256, 0, stream>>>(pt, out, NROWS / 64);
    }
}

// Round 12
// 330.003 us; speedup vs baseline: 1.8813x; 1.0445x over previous
//
#include <hip/hip_runtime.h>

#define KCODES 4096
#define DIM    256
#define NROWS  65536
#define MARGIN 4.0e-4f
#define DSLACK 3.0e-5f
#define LCAP   4096
#define CPAD   32
#define LSTRIDE (DIM + 4)

typedef unsigned long long u64;
typedef unsigned int  uint;
typedef unsigned short ushort;
typedef __attribute__((ext_vector_type(8))) short bf16x8;
typedef __attribute__((ext_vector_type(4))) float f32x4;

typedef __attribute__((address_space(3))) uint lds_u32_t;
typedef __attribute__((address_space(1))) uint glb_u32_t;

__device__ __forceinline__ void g2lds16(const void* g, void* l) {
    __builtin_amdgcn_global_load_lds((const glb_u32_t*)g, (lds_u32_t*)l, 16, 0, 0);
}

// cross-lane mins via DPP (VALU pipe, no LDS)
__device__ __forceinline__ float dppmin_quad(float m) {
    m = fminf(m, __int_as_float(__builtin_amdgcn_update_dpp(0, __float_as_int(m), 0xB1, 0xF, 0xF, true)));
    m = fminf(m, __int_as_float(__builtin_amdgcn_update_dpp(0, __float_as_int(m), 0x4E, 0xF, 0xF, true)));
    return m;
}
__device__ __forceinline__ float dppmin_row16(float m) {
    m = fminf(m, __int_as_float(__builtin_amdgcn_update_dpp(0, __float_as_int(m), 0x124, 0xF, 0xF, true)));
    m = fminf(m, __int_as_float(__builtin_amdgcn_update_dpp(0, __float_as_int(m), 0x128, 0xF, 0xF, true)));
    return m;
}
__device__ __forceinline__ uint dppor_row16(uint v) {
    v |= (uint)__builtin_amdgcn_update_dpp(0, (int)v, 0x124, 0xF, 0xF, true);
    v |= (uint)__builtin_amdgcn_update_dpp(0, (int)v, 0x128, 0xF, 0xF, true);
    return v;
}

// ============================ shared helpers ============================

__device__ __forceinline__ float np_half_sum128(const float4* __restrict__ p4) {
    #pragma clang fp contract(off)
    float4 v0 = p4[0], v1 = p4[1];
    float r0 = v0.x * v0.x, r1 = v0.y * v0.y, r2 = v0.z * v0.z, r3 = v0.w * v0.w;
    float r4 = v1.x * v1.x, r5 = v1.y * v1.y, r6 = v1.z * v1.z, r7 = v1.w * v1.w;
    #pragma unroll
    for (int i = 1; i < 16; ++i) {
        float4 a = p4[2 * i], b = p4[2 * i + 1];
        r0 += a.x * a.x; r1 += a.y * a.y; r2 += a.z * a.z; r3 += a.w * a.w;
        r4 += b.x * b.x; r5 += b.y * b.y; r6 += b.z * b.z; r7 += b.w * b.w;
    }
    return ((r0 + r1) + (r2 + r3)) + ((r4 + r5) + (r6 + r7));
}

__global__ void k_rownorm(const float* __restrict__ src, float* __restrict__ dst, int nrows) {
    int r = blockIdx.x * blockDim.x + threadIdx.x;
    if (r >= nrows) return;
    const float4* p4 = (const float4*)(src + (size_t)r * DIM);
    float s;
    {
        #pragma clang fp contract(off)
        s = np_half_sum128(p4) + np_half_sum128(p4 + 32);
    }
    dst[r] = s;
}

// validated (round 3): fl32( fl32(Cr+ebc) - fl32(2*fl32(cross_exact)) )
__device__ __forceinline__ float f32_dist(float Cr, float ebc, double accv) {
    #pragma clang fp contract(off)
    float A = Cr + ebc;
    float B = 2.0f * (float)accv;
    return A - B;
}

__device__ __forceinline__ ushort f2bf(float f) {
    uint u = __float_as_uint(f);
    return (ushort)((u + 0x7fffu + ((u >> 16) & 1u)) >> 16);
}

// ============================ fast-path kernels ============================

__global__ void k_split(const float* __restrict__ src, ushort* __restrict__ dst, int n8) {
    int i = blockIdx.x * blockDim.x + threadIdx.x;
    if (i >= n8) return;
    const float4* s4 = (const float4*)src;
    float4 a = s4[2 * i], b = s4[2 * i + 1];
    uint4 ov;
    ov.x = (uint)f2bf(a.x) | ((uint)f2bf(a.y) << 16);
    ov.y = (uint)f2bf(a.z) | ((uint)f2bf(a.w) << 16);
    ov.z = (uint)f2bf(b.x) | ((uint)f2bf(b.y) << 16);
    ov.w = (uint)f2bf(b.z) | ((uint)f2bf(b.w) << 16);
    *(uint4*)&dst[8 * i] = ov;
}

__global__ void k_init(int* __restrict__ cnt) {
    cnt[blockIdx.x * 256 + threadIdx.x] = 0;
}

// MFMA filter: z in regs (32 rows/wave), e streamed as 64-code dbuf swizzled
// LDS tiles (2x32KB, 2 blocks/CU). Ping-pong accumulators: tile t's epilogue
// runs AFTER the barrier, at the top of tile t+1 (hidden under ds_read/MFMA).
// Epilogue is Cr-free (Cr cancels in m-mt; added once at tk store).
__global__ __launch_bounds__(256, 2)
void k_gemm(const ushort* __restrict__ zh, const ushort* __restrict__ eh,
            const float* __restrict__ Crow, const float* __restrict__ eb2,
            float* __restrict__ tk, uint* __restrict__ tk2) {
    __shared__ __align__(16) ushort Bs[2][64 * 256];   // 2 x 32KB

    const int t = threadIdx.x;
    const int lane = t & 63;
    const int w = t >> 6;
    const int l15 = lane & 15, l4 = lane >> 4;
    const int row0w = blockIdx.x * 128 + w * 32;

    const char* ebp = (const char*)eh;

    auto stage = [&](int buf, int ct2) {
        const char* base = ebp + (size_t)ct2 * 64 * 512;
        #pragma unroll
        for (int i = 0; i < 8; ++i) {
            int idx = i * 256 + t;
            int code = idx >> 5;
            int c16  = idx & 31;
            int src  = (code << 9) + ((c16 ^ (code & 7)) << 4);
            g2lds16(base + src, (char*)Bs[buf] + idx * 16);
        }
    };

    // ---- A: 32 rows x 256 K in registers (MFMA A-frag layout) ----
    bf16x8 a[2][8];
    #pragma unroll
    for (int f = 0; f < 2; ++f)
        #pragma unroll
        for (int ks = 0; ks < 8; ++ks)
            a[f][ks] = *(const bf16x8*)&zh[(size_t)(row0w + f * 16 + l15) * 256 + ks * 32 + l4 * 8];

    float crf[8];
    #pragma unroll
    for (int f = 0; f < 2; ++f)
        #pragma unroll
        for (int rg = 0; rg < 4; ++rg)
            crf[f * 4 + rg] = Crow[row0w + f * 16 + l4 * 4 + rg];

    float mprev[8];
    const f32x4 fzero = (f32x4){0.f, 0.f, 0.f, 0.f};
    f32x4 accA[2][4], accB[2][4];
    float ebvA[4], ebvB[4];

    auto ksloop = [&](const ushort* Bb, f32x4 (&acc)[2][4]) {
        #pragma unroll
        for (int ks = 0; ks < 8; ++ks) {
            bf16x8 bfv[4];
            #pragma unroll
            for (int cg = 0; cg < 4; ++cg) {
                int rB = cg * 16 + l15;
                int off = rB * 256 + ((ks * 32 + l4 * 8) ^ ((l15 & 7) << 3));
                bfv[cg] = *(const bf16x8*)&Bb[off];
            }
            __builtin_amdgcn_s_setprio(1);
            #pragma unroll
            for (int f = 0; f < 2; ++f)
                #pragma unroll
                for (int cg = 0; cg < 4; ++cg)
                    acc[f][cg] = __builtin_amdgcn_mfma_f32_16x16x32_bf16(
                        a[f][ks], bfv[cg], ks == 0 ? fzero : acc[f][cg], 0, 0, 0);
            __builtin_amdgcn_s_setprio(0);
        }
    };

    // epilogue for tile ct2 (Cr-free mins; Cr added only at tk store)
    auto epi = [&](f32x4 (&acc)[2][4], const float (&ebv)[4], int ct2, bool odd) {
        #pragma unroll
        for (int f = 0; f < 2; ++f) {
            #pragma unroll
            for (int rg = 0; rg < 4; ++rg) {
                float m =    fmaf(-2.0f, acc[f][0][rg], ebv[0]);
                m = fminf(m, fmaf(-2.0f, acc[f][1][rg], ebv[1]));
                m = fminf(m, fmaf(-2.0f, acc[f][2][rg], ebv[2]));
                m = fminf(m, fmaf(-2.0f, acc[f][3][rg], ebv[3]));
                m = dppmin_quad(m);              // quad-subtile min (Cr-free)
                if (!odd) {
                    mprev[f * 4 + rg] = m;
                } else {
                    m = fminf(m, mprev[f * 4 + rg]);   // merge 128-code tile
                    float mt = dppmin_row16(m);
                    int q = (int)((m - mt) * 1e5f);    // Cr cancels in m-mt
                    q = q > 255 ? 255 : q;
                    uint pk = (uint)q << (8 * (l15 >> 2));
                    pk = dppor_row16(pk);
                    if (l15 == 0) {
                        int grow = row0w + f * 16 + l4 * 4 + rg;
                        int tt = ct2 >> 1;
                        tk [(size_t)tt * NROWS + grow] = crf[f * 4 + rg] + mt;
                        tk2[(size_t)tt * NROWS + grow] = pk;
                    }
                }
            }
        }
    };

    stage(0, 0);
    #pragma unroll
    for (int cg = 0; cg < 4; ++cg) ebvA[cg] = eb2[cg * 16 + l15];
    __syncthreads();

    for (int tp = 0; tp < 32; ++tp) {
        int t0 = 2 * tp;
        // ---- even tile t0 (buf 0) ----
        stage(1, t0 + 1);
        if (tp > 0) epi(accB, ebvB, t0 - 1, true);   // deferred odd epilogue
        ksloop(Bs[0], accA);
        __syncthreads();

        // ---- odd tile t0+1 (buf 1) ----
        if (tp < 31) stage(0, t0 + 2);
        #pragma unroll
        for (int cg = 0; cg < 4; ++cg) ebvB[cg] = eb2[(t0 + 1) * 64 + cg * 16 + l15];
        epi(accA, ebvA, t0, false);                  // deferred even epilogue
        if (tp < 31) {
            #pragma unroll
            for (int cg = 0; cg < 4; ++cg) ebvA[cg] = eb2[(t0 + 2) * 64 + cg * 16 + l15];
        }
        ksloop(Bs[1], accB);
        __syncthreads();
    }
    epi(accB, ebvB, 63, true);
}

// per row: rowbest over 32 tile-mins; decode subtile mins; wave-aggregated
// append; padded counters (1 L2 line each); init fkey.
__global__ void k_lists(const float* __restrict__ tk, const uint* __restrict__ tk2,
                        int* __restrict__ cnt, int* __restrict__ list,
                        u64* __restrict__ fkey) {
    int row = blockIdx.x * 256 + threadIdx.x;
    int lane = threadIdx.x & 63;
    float tm[32]; uint pk[32];
    #pragma unroll
    for (int tt = 0; tt < 32; ++tt) {
        tm[tt] = tk [(size_t)tt * NROWS + row];
        pk[tt] = tk2[(size_t)tt * NROWS + row];
    }
    float best = tm[0];
    #pragma unroll
    for (int tt = 1; tt < 32; ++tt) best = fminf(best, tm[tt]);
    fkey[row] = ~0ull;
    float cutoff = best + (MARGIN + DSLACK);

    #pragma unroll
    for (int tt = 0; tt < 32; ++tt) {
        #pragma unroll
        for (int p = 0; p < 4; ++p) {
            float v = tm[tt] + (float)((pk[tt] >> (8 * p)) & 255u) * 1e-5f;
            bool pred = v <= cutoff;
            u64 mask = __ballot(pred);
            if (mask) {
                int sub = tt * 4 + p;
                int nq = __popcll(mask);
                int rank = __popcll(mask & ((1ull << lane) - 1ull));
                int base = 0;
                if (lane == 0) base = atomicAdd(&cnt[sub * CPAD], nq);
                base = __shfl(base, 0, 64);
                int pos = base + rank;
                if (pred && pos < LCAP) list[sub * LCAP + pos] = row;
            }
        }
    }
}

// exact decider; subtile sub = (tile<<2)|quad: codes = tile*128+cg*16+quad*4+r.
// Validated f64-cross + f32_dist + lexicographic (d,idx) key, atomicMin-merged.
__global__ __launch_bounds__(256, 2)
void k_exact(const float* __restrict__ z, const float* __restrict__ e,
             const float* __restrict__ Crow, const float* __restrict__ eb2,
             const int* __restrict__ list, const int* __restrict__ cnt,
             u64* __restrict__ fkey) {
    __shared__ __align__(16) float ex[32][260];
    __shared__ __align__(16) float zx[32][260];
    __shared__ int rows[32];
    __shared__ u64 keytab[32][17];
    const int sub = blockIdx.x;       // 0..127
    const int tile = sub >> 2, qq = sub & 3;
    const int nct = cnt[sub * CPAD];
    const int t = threadIdx.x;
    const int rp = t & 15, cs = t >> 4;

    {   // stage e subtile (32 quad-mapped codes x 256)
        int cc = t >> 3, c8 = t & 7;
        int gcode = tile * 128 + (cc >> 2) * 16 + qq * 4 + (cc & 3);
        const float4* src = (const float4*)(e + (size_t)gcode * DIM);
        float4* dr = (float4*)ex[cc];
        #pragma unroll
        for (int j = 0; j < 8; ++j) dr[c8 + 8 * j] = src[c8 + 8 * j];
    }
    const int gc0 = tile * 128 + (cs >> 2) * 16 + qq * 4 + (cs & 3);
    const int gc1 = tile * 128 + ((cs >> 2) + 4) * 16 + qq * 4 + (cs & 3);
    const float ebc0 = eb2[gc0];
    const float ebc1 = eb2[gc1];

    for (int base = blockIdx.y * 32; base < nct; base += gridDim.y * 32) {
        __syncthreads();
        if (t < 32) {
            int i = base + t;
            rows[t] = list[sub * LCAP + (i < nct ? i : nct - 1)];
        }
        __syncthreads();
        {
            int rr = t >> 3, c8 = t & 7;
            const float4* src = (const float4*)(z + (size_t)rows[rr] * DIM);
            float4* dr = (float4*)zx[rr];
            #pragma unroll
            for (int j = 0; j < 8; ++j) dr[c8 + 8 * j] = src[c8 + 8 * j];
        }
        __syncthreads();

        double a00 = 0.0, a01 = 0.0, a10 = 0.0, a11 = 0.0;
        const float4* z0 = (const float4*)zx[rp];
        const float4* z1 = (const float4*)zx[rp + 16];
        const float4* e0 = (const float4*)ex[cs];
        const float4* e1 = (const float4*)ex[cs + 16];
        #pragma unroll 8
        for (int d4 = 0; d4 < 64; ++d4) {
            float4 x0 = z0[d4], x1 = z1[d4], y0 = e0[d4], y1 = e1[d4];
            a00 += (double)x0.x * (double)y0.x; a00 += (double)x0.y * (double)y0.y;
            a00 += (double)x0.z * (double)y0.z; a00 += (double)x0.w * (double)y0.w;
            a01 += (double)x0.x * (double)y1.x; a01 += (double)x0.y * (double)y1.y;
            a01 += (double)x0.z * (double)y1.z; a01 += (double)x0.w * (double)y1.w;
            a10 += (double)x1.x * (double)y0.x; a10 += (double)x1.y * (double)y0.y;
            a10 += (double)x1.z * (double)y0.z; a10 += (double)x1.w * (double)y0.w;
            a11 += (double)x1.x * (double)y1.x; a11 += (double)x1.y * (double)y1.y;
            a11 += (double)x1.z * (double)y1.z; a11 += (double)x1.w * (double)y1.w;
        }
        int r0 = rows[rp], r1 = rows[rp + 16];
        float C0 = Crow[r0], C1 = Crow[r1];
        u64 k00 = ((u64)__float_as_uint(f32_dist(C0, ebc0, a00)) << 32) | (u64)gc0;
        u64 k01 = ((u64)__float_as_uint(f32_dist(C0, ebc1, a01)) << 32) | (u64)gc1;
        u64 k10 = ((u64)__float_as_uint(f32_dist(C1, ebc0, a10)) << 32) | (u64)gc0;
        u64 k11 = ((u64)__float_as_uint(f32_dist(C1, ebc1, a11)) << 32) | (u64)gc1;
        keytab[rp][cs]      = k00 < k01 ? k00 : k01;
        keytab[rp + 16][cs] = k10 < k11 ? k10 : k11;
        __syncthreads();
        if (t < 32) {
            u64 kb = keytab[t][0];
            #pragma unroll
            for (int j = 1; j < 16; ++j) {
                u64 k = keytab[t][j];
                kb = k < kb ? k : kb;
            }
            atomicMin((unsigned long long*)&fkey[rows[t]], kb);
        }
    }
}

__global__ __launch_bounds__(256)
void k_gather(const float* __restrict__ z, const float* __restrict__ e,
              const u64* __restrict__ fkey, float* __restrict__ out,
              double* __restrict__ partial) {
    __shared__ double lred[4];
    const int t = threadIdx.x;
    const int row = blockIdx.x * 32 + (t >> 3);
    const int c8 = t & 7;
    const int idx = (int)(fkey[row] & 0xffffffffull);
    if (c8 == 0) out[1 + (size_t)NROWS * DIM + row] = (float)idx;
    const float4* zr = (const float4*)(z + (size_t)row * DIM);
    const float4* er = (const float4*)(e + (size_t)idx * DIM);
    float4* orow = (float4*)(out + 1 + (size_t)row * DIM);
    double lacc = 0.0;
    #pragma unroll
    for (int j = 0; j < 8; ++j) {
        float4 q = er[c8 + 8 * j];
        float4 zv = zr[c8 + 8 * j];
        orow[c8 + 8 * j] = q;
        double d0 = (double)q.x - (double)zv.x;
        double d1 = (double)q.y - (double)zv.y;
        double d2 = (double)q.z - (double)zv.z;
        double d3 = (double)q.w - (double)zv.w;
        lacc += d0 * d0 + d1 * d1 + d2 * d2 + d3 * d3;
    }
    for (int off = 32; off > 0; off >>= 1) lacc += __shfl_down(lacc, off, 64);
    if ((t & 63) == 0) lred[t >> 6] = lacc;
    __syncthreads();
    if (t == 0) partial[blockIdx.x] = lred[0] + lred[1] + lred[2] + lred[3];
}

__global__ void k_finish(const double* __restrict__ partial, float* __restrict__ out, int n) {
    __shared__ double s[256];
    double a = 0.0;
    for (int i = threadIdx.x; i < n; i += 256) a += partial[i];
    s[threadIdx.x] = a;
    __syncthreads();
    for (int off = 128; off > 0; off >>= 1) {
        if (threadIdx.x < off) s[threadIdx.x] += s[threadIdx.x + off];
        __syncthreads();
    }
    if (threadIdx.x == 0)
        out[0] = (float)(1.25 * s[0] / ((double)NROWS * (double)DIM));
}

// ===================== fallback (round-3 validated path) =====================

__global__ __launch_bounds__(256, 1)
void k_main_slow(const float* __restrict__ z, const float* __restrict__ e,
                 const float* __restrict__ Crow, const float* __restrict__ eb2,
                 float* __restrict__ out, double* __restrict__ partial) {
    __shared__ float  zt[64][LSTRIDE];
    __shared__ float  et[64][LSTRIDE];
    __shared__ float  redd[64][17];
    __shared__ int    redi[64][17];
    __shared__ int    bsel[64];
    __shared__ double lred[4];

    const int t  = threadIdx.x;
    const int tx = t & 15;
    const int ty = t >> 4;
    const int row0 = blockIdx.x * 64;

    {
        const float4* zsrc = (const float4*)(z + (size_t)row0 * DIM);
        for (int i = t; i < 64 * (DIM / 4); i += 256) {
            int r = i >> 6, c4 = i & 63;
            *(float4*)&zt[r][c4 * 4] = zsrc[r * (DIM / 4) + c4];
        }
    }
    float Cr[4];
    #pragma unroll
    for (int ri = 0; ri < 4; ++ri) Cr[ri] = Crow[row0 + ty * 4 + ri];
    float bestd[4]; int besti[4];
    #pragma unroll
    for (int ri = 0; ri < 4; ++ri) { bestd[ri] = __int_as_float(0x7f800000); besti[ri] = 0; }

    for (int kt = 0; kt < KCODES / 64; ++kt) {
        __syncthreads();
        {
            const float4* esrc = (const float4*)(e + (size_t)kt * 64 * DIM);
            for (int i = t; i < 64 * (DIM / 4); i += 256) {
                int r = i >> 6, c4 = i & 63;
                *(float4*)&et[r][c4 * 4] = esrc[r * (DIM / 4) + c4];
            }
        }
        __syncthreads();
        double acc[4][4];
        #pragma unroll
        for (int a = 0; a < 4; ++a)
            #pragma unroll
            for (int b = 0; b < 4; ++b) acc[a][b] = 0.0;
        #pragma unroll 4
        for (int d4 = 0; d4 < DIM / 4; ++d4) {
            float4 za[4], ea[4];
            #pragma unroll
            for (int ri = 0; ri < 4; ++ri) za[ri] = *(const float4*)&zt[ty * 4 + ri][d4 * 4];
            #pragma unroll
            for (int ci = 0; ci < 4; ++ci) ea[ci] = *(const float4*)&et[tx + 16 * ci][d4 * 4];
            #pragma unroll
            for (int ri = 0; ri < 4; ++ri)
                #pragma unroll
                for (int ci = 0; ci < 4; ++ci)
                    acc[ri][ci] += (double)za[ri].x * (double)ea[ci].x
                                 + (double)za[ri].y * (double)ea[ci].y
                                 + (double)za[ri].z * (double)ea[ci].z
                                 + (double)za[ri].w * (double)ea[ci].w;
        }
        #pragma unroll
        for (int ci = 0; ci < 4; ++ci) {
            int c = kt * 64 + tx + 16 * ci;
            float ebc = eb2[c];
            #pragma unroll
            for (int ri = 0; ri < 4; ++ri) {
                float d = f32_dist(Cr[ri], ebc, acc[ri][ci]);
                if (d < bestd[ri]) { bestd[ri] = d; besti[ri] = c; }
            }
        }
    }
    __syncthreads();
    #pragma unroll
    for (int ri = 0; ri < 4; ++ri) {
        redd[ty * 4 + ri][tx] = bestd[ri];
        redi[ty * 4 + ri][tx] = besti[ri];
    }
    __syncthreads();
    if (t < 64) {
        float bd = redd[t][0]; int bi = redi[t][0];
        for (int j = 1; j < 16; ++j) {
            float d = redd[t][j]; int i2 = redi[t][j];
            if (d < bd || (d == bd && i2 < bi)) { bd = d; bi = i2; }
        }
        bsel[t] = bi;
        out[1 + (size_t)NROWS * DIM + row0 + t] = (float)bi;
    }
    __syncthreads();
    double lacc = 0.0;
    {
        int r = t >> 2, qd = (t & 3) * 64;
        int bi = bsel[r];
        const float* qrow = e + (size_t)bi * DIM + qd;
        float* orow = out + 1 + (size_t)(row0 + r) * DIM + qd;
        #pragma unroll 4
        for (int d = 0; d < 64; ++d) {
            float qv = qrow[d], zv = zt[r][qd + d];
            double df = (double)qv - (double)zv;
            lacc += df * df;
            orow[d] = qv;
        }
    }
    for (int off = 32; off > 0; off >>= 1) lacc += __shfl_down(lacc, off, 64);
    if ((t & 63) == 0) lred[t >> 6] = lacc;
    __syncthreads();
    if (t == 0) partial[blockIdx.x] = lred[0] + lred[1] + lred[2] + lred[3];
}

// ============================ launch ============================

extern "C" void kernel_launch(void* const* d_in, const int* in_sizes, int n_in,
                              void* d_out, int out_size, void* d_ws, size_t ws_size,
                              hipStream_t stream) {
    const float* z = (const float*)d_in[0];
    const float* e = (const float*)d_in[1];
    float* out = (float*)d_out;
    char* w = (char*)d_ws;

    size_t o = 0;
    auto take = [&](size_t b) { size_t r = o; o = (o + b + 255) & ~(size_t)255; return r; };
    size_t o_zh = take((size_t)NROWS * DIM * 2);
    size_t o_eh = take((size_t)KCODES * DIM * 2);
    size_t o_cr = take((size_t)NROWS * 4);
    size_t o_eb = take((size_t)KCODES * 4);
    size_t o_tk = take((size_t)32 * NROWS * 4);
    size_t o_t2 = take((size_t)32 * NROWS * 4);
    size_t o_fk = take((size_t)NROWS * 8);
    size_t o_cn = take((size_t)128 * CPAD * 4);
    size_t o_ls = take((size_t)128 * LCAP * 4);
    size_t o_pt = take((size_t)2048 * 8);
    size_t need = o;

    if (ws_size >= need) {
        ushort* zh = (ushort*)(w + o_zh);
        ushort* eh = (ushort*)(w + o_eh);
        float* Cr  = (float*)(w + o_cr);
        float* eb  = (float*)(w + o_eb);
        float* tk  = (float*)(w + o_tk);
        uint*  tk2 = (uint*)(w + o_t2);
        u64*   fk  = (u64*)(w + o_fk);
        int*   cn  = (int*)(w + o_cn);
        int*   ls  = (int*)(w + o_ls);
        double* pt = (double*)(w + o_pt);

        k_split<<<NROWS * DIM / 8 / 256, 256, 0, stream>>>(z, zh, NROWS * DIM / 8);
        k_split<<<KCODES * DIM / 8 / 256, 256, 0, stream>>>(e, eh, KCODES * DIM / 8);
        k_rownorm<<<NROWS / 256, 256, 0, stream>>>(z, Cr, NROWS);
        k_rownorm<<<KCODES / 256, 256, 0, stream>>>(e, eb, KCODES);
        k_init<<<(128 * CPAD) / 256, 256, 0, stream>>>(cn);
        k_gemm<<<NROWS / 128, 256, 0, stream>>>(zh, eh, Cr, eb, tk, tk2);
        k_lists<<<NROWS / 256, 256, 0, stream>>>(tk, tk2, cn, ls, fk);
        dim3 ge(128, 16);
        k_exact<<<ge, 256, 0, stream>>>(z, e, Cr, eb, ls, cn, fk);
        k_gather<<<NROWS / 32, 256, 0, stream>>>(z, e, fk, out, pt);
        k_finish<<<1, 256, 0, stream>>>(pt, out, 2048);
    } else {
        float* Cr  = (float*)w;
        float* eb  = Cr + NROWS;
        double* pt = (double*)(eb + KCODES);
        k_rownorm<<<NROWS / 256, 256, 0, stream>>>(z, Cr, NROWS);
        k_rownorm<<<KCODES / 256, 256, 0, stream>>>(e, eb, KCODES);
        k_main_slow<<<NROWS / 64, 256, 0, stream>>>(z, e, Cr, eb, out, pt);
        k_finish<<<1, 256, 0, stream>>>(pt, out, NROWS / 64);
    }
}